// Round 1
// baseline (34670.248 us; speedup 1.0000x reference)
//
#include <hip/hip_runtime.h>
#include <math.h>

#define NB 8
#define NH 256
#define NW 256
#define NC 64
#define HP 128
#define WP 128

// db4 analysis filters (lo = c_h, hi = c_g with g[k] = (-1)^k h[7-k])
__constant__ float c_h[8] = {
  -0.010597401784997278f, 0.032883011666982945f, 0.030841381835986965f,
  -0.18703481171888114f, -0.02798376941698385f, 0.6308807679295904f,
   0.7148465705525415f,   0.23037781330885523f};
__constant__ float c_g[8] = {
   0.23037781330885523f, -0.7148465705525415f,  0.6308807679295904f,
   0.02798376941698385f, -0.18703481171888114f, -0.030841381835986965f,
   0.032883011666982945f, 0.010597401784997278f};

// ---------------- K1: 2x2 maxpool ----------------
__global__ __launch_bounds__(256) void k_maxpool(const float* __restrict__ img,
                                                 float* __restrict__ mp) {
  int idx = blockIdx.x * 256 + threadIdx.x;   // 8*128*128*64 = 8388608
  int c  = idx & 63;
  int wp = (idx >> 6) & 127;
  int hp = (idx >> 13) & 127;
  int b  = idx >> 20;
  const float* p = img + (((size_t)b * NH + 2 * hp) * NW + 2 * wp) * NC + c;
  float v0 = p[0], v1 = p[NC], v2 = p[(size_t)NW * NC], v3 = p[(size_t)NW * NC + NC];
  mp[idx] = fmaxf(fmaxf(v0, v1), fmaxf(v2, v3));
}

// ---------------- K2a: DWT along H ----------------
__global__ __launch_bounds__(256) void k_dwt_h(const float* __restrict__ mp,
                                               float* __restrict__ tLo,
                                               float* __restrict__ tHi) {
  int idx = blockIdx.x * 256 + threadIdx.x;   // 8*64*128*64 = 4194304
  int c = idx & 63;
  int w = (idx >> 6) & 127;
  int m = (idx >> 13) & 63;
  int b = idx >> 19;
  const float* base = mp + (size_t)b * (HP * WP * NC) + (size_t)w * NC + c;
  float lo = 0.f, hi = 0.f;
  #pragma unroll
  for (int k = 0; k < 8; ++k) {
    int r = (2 * m + k) & 127;
    float v = base[(size_t)r * (WP * NC)];
    lo += c_h[k] * v;
    hi += c_g[k] * v;
  }
  tLo[idx] = lo;   // [b][m][w][c]
  tHi[idx] = hi;
}

// ---------------- K2b: DWT along W -> 4 bands ----------------
__global__ __launch_bounds__(256) void k_dwt_w(const float* __restrict__ tLo,
                                               const float* __restrict__ tHi,
                                               float* __restrict__ bands) {
  int idx = blockIdx.x * 256 + threadIdx.x;   // 8*64*64*64 = 2097152
  int c = idx & 63;
  int u = (idx >> 6) & 63;
  int m = (idx >> 12) & 63;
  int b = idx >> 18;
  size_t rowbase = ((size_t)(b * 64 + m) * 128) * NC + c;
  float ll = 0.f, lh = 0.f, hl = 0.f, hh = 0.f;
  #pragma unroll
  for (int k = 0; k < 8; ++k) {
    int w = (2 * u + k) & 127;
    float a = tLo[rowbase + (size_t)w * NC];
    float d = tHi[rowbase + (size_t)w * NC];
    ll += c_h[k] * a;  lh += c_g[k] * a;
    hl += c_h[k] * d;  hh += c_g[k] * d;
  }
  const size_t bs = 2097152;  // 8*64*64*64
  bands[0 * bs + idx] = ll;
  bands[1 * bs + idx] = lh;
  bands[2 * bs + idx] = hl;
  bands[3 * bs + idx] = hh;
}

// ---------------- K3: per-(band,batch) Gram G = fb^T fb ----------------
__global__ __launch_bounds__(256) void k_gram(const float* __restrict__ bands,
                                              float* __restrict__ G) {
  int blk = blockIdx.x;                        // = band*8 + b, 32 blocks
  const float* fb = bands + (size_t)blk * 262144;  // [4096][64]
  __shared__ float fbs[64][64];
  int t = threadIdx.x;
  int c2 = t & 63;
  int a  = t >> 6;        // 0..3 (wave id)
  float acc[16];
  #pragma unroll
  for (int q = 0; q < 16; ++q) acc[q] = 0.f;
  #pragma unroll 1
  for (int chunk = 0; chunk < 64; ++chunk) {
    #pragma unroll
    for (int i = 0; i < 16; ++i) {
      int e = t + i * 256;
      fbs[e >> 6][e & 63] = fb[(size_t)chunk * 4096 + e];
    }
    __syncthreads();
    #pragma unroll 1
    for (int rr = 0; rr < 64; ++rr) {
      float v2 = fbs[rr][c2];
      const float4* row4 = (const float4*)&fbs[rr][a * 16];
      #pragma unroll
      for (int q4 = 0; q4 < 4; ++q4) {
        float4 va = row4[q4];
        acc[q4 * 4 + 0] += va.x * v2;
        acc[q4 * 4 + 1] += va.y * v2;
        acc[q4 * 4 + 2] += va.z * v2;
        acc[q4 * 4 + 3] += va.w * v2;
      }
    }
    __syncthreads();
  }
  #pragma unroll
  for (int q = 0; q < 16; ++q)
    G[(size_t)blk * 4096 + (a * 16 + q) * 64 + c2] = acc[q];
}

// ---------------- K4: att = softmax(Wq^T G Wk / 8); M = Wv @ att ----------------
__global__ __launch_bounds__(256) void k_att(const float* __restrict__ G,
                                             const float* __restrict__ Wq,
                                             const float* __restrict__ Wk,
                                             const float* __restrict__ Wv,
                                             float* __restrict__ Mout) {
  int blk = blockIdx.x;        // band*8 + b
  int band = blk >> 3;
  __shared__ float Gs[64][68];
  __shared__ float As[64][68];
  __shared__ float Bs[64][68];
  int t = threadIdx.x;
  #pragma unroll
  for (int p = 0; p < 16; ++p) {
    int e = t + p * 256;
    Gs[e >> 6][e & 63] = G[(size_t)blk * 4096 + e];
    As[e >> 6][e & 63] = Wk[(size_t)band * 4096 + e];
  }
  __syncthreads();
  int r  = t >> 2;
  int d0 = (t & 3) << 4;
  float acc[16];
  // T1 = G @ Wk
  #pragma unroll
  for (int q = 0; q < 16; ++q) acc[q] = 0.f;
  #pragma unroll 1
  for (int e = 0; e < 64; ++e) {
    float gv = Gs[r][e];
    const float4* wr = (const float4*)&As[e][d0];
    #pragma unroll
    for (int q4 = 0; q4 < 4; ++q4) {
      float4 wv = wr[q4];
      acc[q4*4+0] += gv * wv.x; acc[q4*4+1] += gv * wv.y;
      acc[q4*4+2] += gv * wv.z; acc[q4*4+3] += gv * wv.w;
    }
  }
  __syncthreads();   // all reads of As(Wk)/Gs done
  #pragma unroll
  for (int q = 0; q < 16; ++q) Bs[r][d0 + q] = acc[q];
  #pragma unroll
  for (int p = 0; p < 16; ++p) {
    int e = t + p * 256;
    As[e >> 6][e & 63] = Wq[(size_t)band * 4096 + e];
  }
  __syncthreads();
  // att = Wq^T T1 / 8
  #pragma unroll
  for (int q = 0; q < 16; ++q) acc[q] = 0.f;
  #pragma unroll 1
  for (int e = 0; e < 64; ++e) {
    float qv = As[e][r];
    const float4* tr = (const float4*)&Bs[e][d0];
    #pragma unroll
    for (int q4 = 0; q4 < 4; ++q4) {
      float4 tv = tr[q4];
      acc[q4*4+0] += qv * tv.x; acc[q4*4+1] += qv * tv.y;
      acc[q4*4+2] += qv * tv.z; acc[q4*4+3] += qv * tv.w;
    }
  }
  #pragma unroll
  for (int q = 0; q < 16; ++q) acc[q] *= 0.125f;
  // softmax over row r (4 lanes per row)
  float mx = acc[0];
  #pragma unroll
  for (int q = 1; q < 16; ++q) mx = fmaxf(mx, acc[q]);
  mx = fmaxf(mx, __shfl_xor(mx, 1));
  mx = fmaxf(mx, __shfl_xor(mx, 2));
  float s = 0.f;
  #pragma unroll
  for (int q = 0; q < 16; ++q) { acc[q] = expf(acc[q] - mx); s += acc[q]; }
  s += __shfl_xor(s, 1);
  s += __shfl_xor(s, 2);
  float inv = 1.f / s;
  #pragma unroll
  for (int q = 0; q < 16; ++q) acc[q] *= inv;
  __syncthreads();   // all reads of As(Wq)/Bs done
  #pragma unroll
  for (int q = 0; q < 16; ++q) Gs[r][d0 + q] = acc[q];  // Gs := att
  #pragma unroll
  for (int p = 0; p < 16; ++p) {
    int e = t + p * 256;
    As[e >> 6][e & 63] = Wv[e];
  }
  __syncthreads();
  // M = Wv @ att
  #pragma unroll
  for (int q = 0; q < 16; ++q) acc[q] = 0.f;
  #pragma unroll 1
  for (int e = 0; e < 64; ++e) {
    float wv = As[r][e];
    const float4* ar = (const float4*)&Gs[e][d0];
    #pragma unroll
    for (int q4 = 0; q4 < 4; ++q4) {
      float4 av = ar[q4];
      acc[q4*4+0] += wv * av.x; acc[q4*4+1] += wv * av.y;
      acc[q4*4+2] += wv * av.z; acc[q4*4+3] += wv * av.w;
    }
  }
  #pragma unroll
  for (int q = 0; q < 16; ++q)
    Mout[(size_t)blk * 4096 + r * 64 + d0 + q] = acc[q];
}

// ---------------- K5: fused W-axis IDWT + channel mix -> lo, hi ----------------
// lo[b][h][n][:] = u0[n]@M0 + u1[n]@M1 ; hi[b][h][n][:] = u0[n]@M2 + u1[n]@M3
// u0[n][a] = sum_j c_h[n%2+2j] * mp[b][h][(n>>1 - j)&127][a]   (u1 with c_g)
__global__ __launch_bounds__(512) void k_wmerge(const float* __restrict__ mp,
                                                const float* __restrict__ M,
                                                float* __restrict__ lo,
                                                float* __restrict__ hi) {
  int b = blockIdx.x >> 7;
  int h = blockIdx.x & 127;
  __shared__ float mps[128][65];
  __shared__ float Ms[4][64][64];
  int t = threadIdx.x;
  // stage mp row [128][64]
  const float* mrow = mp + (size_t)(b * 128 + h) * (WP * NC);
  #pragma unroll
  for (int i = 0; i < 16; ++i) {
    int e = t + i * 512;
    mps[e >> 6][e & 63] = mrow[e];
  }
  // stage M0..M3 for batch b
  #pragma unroll
  for (int i = 0; i < 32; ++i) {
    int e = t + i * 512;           // 0..16383
    int mat = e >> 12;
    Ms[mat][(e >> 6) & 63][e & 63] = M[((size_t)(mat * 8 + b) << 12) + (e & 4095)];
  }
  __syncthreads();
  int half = t >> 8;       // 0 -> lo, 1 -> hi
  int n    = t & 255;
  int par  = n & 1;
  int mj[4]; float cl[4], cg[4];
  #pragma unroll
  for (int j = 0; j < 4; ++j) {
    mj[j] = ((n >> 1) - j) & 127;
    cl[j] = c_h[par + 2 * j];
    cg[j] = c_g[par + 2 * j];
  }
  const int ma = half * 2, mb = half * 2 + 1;
  float acc[64];
  #pragma unroll
  for (int q = 0; q < 64; ++q) acc[q] = 0.f;
  #pragma unroll 1
  for (int a_ = 0; a_ < 64; ++a_) {
    float v0 = mps[mj[0]][a_], v1 = mps[mj[1]][a_];
    float v2 = mps[mj[2]][a_], v3 = mps[mj[3]][a_];
    float u0 = cl[0]*v0 + cl[1]*v1 + cl[2]*v2 + cl[3]*v3;
    float u1 = cg[0]*v0 + cg[1]*v1 + cg[2]*v2 + cg[3]*v3;
    const float4* r0 = (const float4*)Ms[ma][a_];
    const float4* r1 = (const float4*)Ms[mb][a_];
    #pragma unroll
    for (int q = 0; q < 16; ++q) {
      float4 w0 = r0[q], w1 = r1[q];
      acc[4*q+0] += u0*w0.x + u1*w1.x;
      acc[4*q+1] += u0*w0.y + u1*w1.y;
      acc[4*q+2] += u0*w0.z + u1*w1.z;
      acc[4*q+3] += u0*w0.w + u1*w1.w;
    }
  }
  float* dst = (half ? hi : lo) + ((size_t)(b * 128 + h) * 256 + n) * NC;
  #pragma unroll
  for (int q = 0; q < 16; ++q)
    ((float4*)dst)[q] = make_float4(acc[4*q+0], acc[4*q+1], acc[4*q+2], acc[4*q+3]);
}

// ---------------- K6: depthwise conv + H-axis IDWT -> x (= path_a+path_b) ----------------
__global__ __launch_bounds__(512) void k_convmerge(const float* __restrict__ img,
                                                   const float* __restrict__ ker,
                                                   const float* __restrict__ lo,
                                                   const float* __restrict__ hi,
                                                   float* __restrict__ x) {
  int b = blockIdx.x >> 7;
  int r = blockIdx.x & 127;      // output rows 2r, 2r+1
  __shared__ float ks[49][64];
  int t = threadIdx.x;
  #pragma unroll
  for (int i = 0; i < 7; ++i) {
    int e = t + i * 512;
    if (e < 3136) ks[e >> 6][e & 63] = ker[e];
  }
  __syncthreads();
  int c = t & 63;
  int s = t >> 6;        // 8 strips of 32 cols
  int w0 = s * 32;
  #pragma unroll 1
  for (int nn = 0; nn < 2; ++nn) {
    int n = 2 * r + nn;
    float acc[32];
    #pragma unroll
    for (int q = 0; q < 32; ++q) acc[q] = 0.f;
    // depthwise conv, SAME zero padding
    #pragma unroll 1
    for (int dy = 0; dy < 7; ++dy) {
      int row = n - 3 + dy;
      if (row < 0 || row >= NH) continue;
      const float* ibase = img + ((size_t)(b * NH + row) * NW) * NC + c;
      float win[38];
      #pragma unroll
      for (int i2 = 0; i2 < 38; ++i2) {
        int col = w0 - 3 + i2;
        win[i2] = (col >= 0 && col < NW) ? ibase[(size_t)col * NC] : 0.f;
      }
      #pragma unroll
      for (int dx = 0; dx < 7; ++dx) {
        float kv = ks[dy * 7 + dx][c];
        #pragma unroll
        for (int ww = 0; ww < 32; ++ww) acc[ww] += kv * win[ww + dx];
      }
    }
    // H-merge: rows (r-j)&127 of lo/hi
    int par = n & 1;
    #pragma unroll
    for (int j = 0; j < 4; ++j) {
      int mrow = (r - j) & 127;
      float clv = c_h[par + 2 * j];
      float cgv = c_g[par + 2 * j];
      const float* lb = lo + ((size_t)(b * 128 + mrow) * 256 + w0) * NC + c;
      const float* hb = hi + ((size_t)(b * 128 + mrow) * 256 + w0) * NC + c;
      #pragma unroll
      for (int ww = 0; ww < 32; ++ww)
        acc[ww] += clv * lb[(size_t)ww * NC] + cgv * hb[(size_t)ww * NC];
    }
    float* xb = x + ((size_t)(b * NH + n) * NW + w0) * NC + c;
    #pragma unroll
    for (int ww = 0; ww < 32; ++ww) xb[(size_t)ww * NC] = acc[ww];
  }
}

// ---------------- K7: in-place LayerNorm + MLP (64 -> 256 GELU -> 64) ----------------
__global__ __launch_bounds__(512) void k_mlp(const float* __restrict__ xin,
                                             const float* __restrict__ gamma,
                                             const float* __restrict__ beta,
                                             const float* __restrict__ W1,
                                             const float* __restrict__ b1,
                                             const float* __restrict__ W2,
                                             const float* __restrict__ b2,
                                             float* __restrict__ out) {
  __shared__ float W1s[64][256];
  __shared__ float W2s[256][64];
  int t = threadIdx.x;
  #pragma unroll
  for (int i = 0; i < 32; ++i) {
    int e = t + i * 512;
    ((float*)W1s)[e] = W1[e];
    ((float*)W2s)[e] = W2[e];
  }
  __syncthreads();
  size_t pix = (size_t)blockIdx.x * 512 + t;
  const float* xp = xin + pix * 64;
  float xv[64];
  #pragma unroll
  for (int q = 0; q < 16; ++q) {
    float4 v = ((const float4*)xp)[q];
    xv[4*q+0] = v.x; xv[4*q+1] = v.y; xv[4*q+2] = v.z; xv[4*q+3] = v.w;
  }
  float mu = 0.f;
  #pragma unroll
  for (int i = 0; i < 64; ++i) mu += xv[i];
  mu *= 0.015625f;
  float var = 0.f;
  #pragma unroll
  for (int i = 0; i < 64; ++i) { float d = xv[i] - mu; var += d * d; }
  var *= 0.015625f;
  float rs = rsqrtf(var + 1e-3f);
  #pragma unroll
  for (int i = 0; i < 64; ++i) xv[i] = (xv[i] - mu) * rs * gamma[i] + beta[i];
  float o[64];
  #pragma unroll
  for (int d = 0; d < 64; ++d) o[d] = b2[d];
  #pragma unroll 1
  for (int jc = 0; jc < 256; jc += 8) {
    float hj[8];
    #pragma unroll
    for (int q = 0; q < 8; ++q) hj[q] = b1[jc + q];
    #pragma unroll
    for (int e = 0; e < 64; ++e) {
      float xe = xv[e];
      const float4* wr = (const float4*)&W1s[e][jc];
      float4 w0 = wr[0], w1 = wr[1];
      hj[0] += xe * w0.x; hj[1] += xe * w0.y; hj[2] += xe * w0.z; hj[3] += xe * w0.w;
      hj[4] += xe * w1.x; hj[5] += xe * w1.y; hj[6] += xe * w1.z; hj[7] += xe * w1.w;
    }
    #pragma unroll
    for (int q = 0; q < 8; ++q) {
      float hv = hj[q];
      float gl = 0.5f * hv * (1.f + erff(hv * 0.70710678118654752f));
      const float4* w2r = (const float4*)&W2s[jc + q][0];
      #pragma unroll
      for (int d4 = 0; d4 < 16; ++d4) {
        float4 wv = w2r[d4];
        o[4*d4+0] += gl * wv.x; o[4*d4+1] += gl * wv.y;
        o[4*d4+2] += gl * wv.z; o[4*d4+3] += gl * wv.w;
      }
    }
  }
  float* op = out + pix * 64;
  #pragma unroll
  for (int q = 0; q < 16; ++q)
    ((float4*)op)[q] = make_float4(o[4*q+0], o[4*q+1], o[4*q+2], o[4*q+3]);
}

extern "C" void kernel_launch(void* const* d_in, const int* in_sizes, int n_in,
                              void* d_out, int out_size, void* d_ws, size_t ws_size,
                              hipStream_t stream) {
  const float* images = (const float*)d_in[0];
  const float* dwk    = (const float*)d_in[1];
  const float* Wv     = (const float*)d_in[2];
  const float* Wq     = (const float*)d_in[3];
  const float* Wk     = (const float*)d_in[4];
  const float* gamma  = (const float*)d_in[5];
  const float* beta   = (const float*)d_in[6];
  const float* W1     = (const float*)d_in[7];
  const float* b1     = (const float*)d_in[8];
  const float* W2     = (const float*)d_in[9];
  const float* b2     = (const float*)d_in[10];
  float* out = (float*)d_out;
  float* ws  = (float*)d_ws;

  float* mp    = ws;                  // 8,388,608
  float* bands = ws + 8388608;        // 8,388,608 (4 bands)
  float* G     = ws + 16777216;       // 131,072
  float* Mm    = ws + 16908288;       // 131,072
  float* lo    = ws + 17039360;       // 16,777,216
  float* hi    = ws + 33816576;       // 16,777,216
  float* tLo   = lo;                  // DWT temps alias lo/hi (dead before overwrite)
  float* tHi   = hi;

  k_maxpool<<<32768, 256, 0, stream>>>(images, mp);
  k_dwt_h<<<16384, 256, 0, stream>>>(mp, tLo, tHi);
  k_dwt_w<<<8192, 256, 0, stream>>>(tLo, tHi, bands);
  k_gram<<<32, 256, 0, stream>>>(bands, G);
  k_att<<<32, 256, 0, stream>>>(G, Wq, Wk, Wv, Mm);
  k_wmerge<<<1024, 512, 0, stream>>>(mp, Mm, lo, hi);
  k_convmerge<<<1024, 512, 0, stream>>>(images, dwk, lo, hi, out);
  k_mlp<<<1024, 512, 0, stream>>>(out, gamma, beta, W1, b1, W2, b2, out);
}

// Round 2
// 14856.305 us; speedup vs baseline: 2.3337x; 2.3337x over previous
//
#include <hip/hip_runtime.h>
#include <math.h>

#define NB 8
#define NH 256
#define NW 256
#define NC 64
#define HP 128
#define WP 128

// db4 analysis filters (lo = c_h, hi = c_g with g[k] = (-1)^k h[7-k])
__constant__ float c_h[8] = {
  -0.010597401784997278f, 0.032883011666982945f, 0.030841381835986965f,
  -0.18703481171888114f, -0.02798376941698385f, 0.6308807679295904f,
   0.7148465705525415f,   0.23037781330885523f};
__constant__ float c_g[8] = {
   0.23037781330885523f, -0.7148465705525415f,  0.6308807679295904f,
   0.02798376941698385f, -0.18703481171888114f, -0.030841381835986965f,
   0.032883011666982945f, 0.010597401784997278f};

// ---------------- K1: 2x2 maxpool ----------------
__global__ __launch_bounds__(256) void k_maxpool(const float* __restrict__ img,
                                                 float* __restrict__ mp) {
  int idx = blockIdx.x * 256 + threadIdx.x;   // 8*128*128*64 = 8388608
  int c  = idx & 63;
  int wp = (idx >> 6) & 127;
  int hp = (idx >> 13) & 127;
  int b  = idx >> 20;
  const float* p = img + (((size_t)b * NH + 2 * hp) * NW + 2 * wp) * NC + c;
  float v0 = p[0], v1 = p[NC], v2 = p[(size_t)NW * NC], v3 = p[(size_t)NW * NC + NC];
  mp[idx] = fmaxf(fmaxf(v0, v1), fmaxf(v2, v3));
}

// ---------------- K2a: DWT along H ----------------
__global__ __launch_bounds__(256) void k_dwt_h(const float* __restrict__ mp,
                                               float* __restrict__ tLo,
                                               float* __restrict__ tHi) {
  int idx = blockIdx.x * 256 + threadIdx.x;   // 8*64*128*64 = 4194304
  int c = idx & 63;
  int w = (idx >> 6) & 127;
  int m = (idx >> 13) & 63;
  int b = idx >> 19;
  const float* base = mp + (size_t)b * (HP * WP * NC) + (size_t)w * NC + c;
  float lo = 0.f, hi = 0.f;
  #pragma unroll
  for (int k = 0; k < 8; ++k) {
    int r = (2 * m + k) & 127;
    float v = base[(size_t)r * (WP * NC)];
    lo += c_h[k] * v;
    hi += c_g[k] * v;
  }
  tLo[idx] = lo;   // [b][m][w][c]
  tHi[idx] = hi;
}

// ---------------- K2b: DWT along W -> 4 bands ----------------
__global__ __launch_bounds__(256) void k_dwt_w(const float* __restrict__ tLo,
                                               const float* __restrict__ tHi,
                                               float* __restrict__ bands) {
  int idx = blockIdx.x * 256 + threadIdx.x;   // 8*64*64*64 = 2097152
  int c = idx & 63;
  int u = (idx >> 6) & 63;
  int m = (idx >> 12) & 63;
  int b = idx >> 18;
  size_t rowbase = ((size_t)(b * 64 + m) * 128) * NC + c;
  float ll = 0.f, lh = 0.f, hl = 0.f, hh = 0.f;
  #pragma unroll
  for (int k = 0; k < 8; ++k) {
    int w = (2 * u + k) & 127;
    float a = tLo[rowbase + (size_t)w * NC];
    float d = tHi[rowbase + (size_t)w * NC];
    ll += c_h[k] * a;  lh += c_g[k] * a;
    hl += c_h[k] * d;  hh += c_g[k] * d;
  }
  const size_t bs = 2097152;  // 8*64*64*64
  bands[0 * bs + idx] = ll;
  bands[1 * bs + idx] = lh;
  bands[2 * bs + idx] = hl;
  bands[3 * bs + idx] = hh;
}

// ---------------- K3: per-(band,batch) Gram G = fb^T fb ----------------
__global__ __launch_bounds__(256) void k_gram(const float* __restrict__ bands,
                                              float* __restrict__ G) {
  int blk = blockIdx.x;                        // = band*8 + b, 32 blocks
  const float* fb = bands + (size_t)blk * 262144;  // [4096][64]
  __shared__ float fbs[64][64];
  int t = threadIdx.x;
  int c2 = t & 63;
  int a  = t >> 6;        // 0..3 (wave id)
  float acc[16];
  #pragma unroll
  for (int q = 0; q < 16; ++q) acc[q] = 0.f;
  #pragma unroll 1
  for (int chunk = 0; chunk < 64; ++chunk) {
    #pragma unroll
    for (int i = 0; i < 16; ++i) {
      int e = t + i * 256;
      fbs[e >> 6][e & 63] = fb[(size_t)chunk * 4096 + e];
    }
    __syncthreads();
    #pragma unroll 1
    for (int rr = 0; rr < 64; ++rr) {
      float v2 = fbs[rr][c2];
      const float4* row4 = (const float4*)&fbs[rr][a * 16];
      #pragma unroll
      for (int q4 = 0; q4 < 4; ++q4) {
        float4 va = row4[q4];
        acc[q4 * 4 + 0] += va.x * v2;
        acc[q4 * 4 + 1] += va.y * v2;
        acc[q4 * 4 + 2] += va.z * v2;
        acc[q4 * 4 + 3] += va.w * v2;
      }
    }
    __syncthreads();
  }
  #pragma unroll
  for (int q = 0; q < 16; ++q)
    G[(size_t)blk * 4096 + (a * 16 + q) * 64 + c2] = acc[q];
}

// ---------------- K4: att = softmax(Wq^T G Wk / 8); M = Wv @ att ----------------
__global__ __launch_bounds__(256) void k_att(const float* __restrict__ G,
                                             const float* __restrict__ Wq,
                                             const float* __restrict__ Wk,
                                             const float* __restrict__ Wv,
                                             float* __restrict__ Mout) {
  int blk = blockIdx.x;        // band*8 + b
  int band = blk >> 3;
  __shared__ float Gs[64][68];
  __shared__ float As[64][68];
  __shared__ float Bs[64][68];
  int t = threadIdx.x;
  #pragma unroll
  for (int p = 0; p < 16; ++p) {
    int e = t + p * 256;
    Gs[e >> 6][e & 63] = G[(size_t)blk * 4096 + e];
    As[e >> 6][e & 63] = Wk[(size_t)band * 4096 + e];
  }
  __syncthreads();
  int r  = t >> 2;
  int d0 = (t & 3) << 4;
  float acc[16];
  // T1 = G @ Wk
  #pragma unroll
  for (int q = 0; q < 16; ++q) acc[q] = 0.f;
  #pragma unroll 1
  for (int e = 0; e < 64; ++e) {
    float gv = Gs[r][e];
    const float4* wr = (const float4*)&As[e][d0];
    #pragma unroll
    for (int q4 = 0; q4 < 4; ++q4) {
      float4 wv = wr[q4];
      acc[q4*4+0] += gv * wv.x; acc[q4*4+1] += gv * wv.y;
      acc[q4*4+2] += gv * wv.z; acc[q4*4+3] += gv * wv.w;
    }
  }
  __syncthreads();   // all reads of As(Wk)/Gs done
  #pragma unroll
  for (int q = 0; q < 16; ++q) Bs[r][d0 + q] = acc[q];
  #pragma unroll
  for (int p = 0; p < 16; ++p) {
    int e = t + p * 256;
    As[e >> 6][e & 63] = Wq[(size_t)band * 4096 + e];
  }
  __syncthreads();
  // att = Wq^T T1 / 8
  #pragma unroll
  for (int q = 0; q < 16; ++q) acc[q] = 0.f;
  #pragma unroll 1
  for (int e = 0; e < 64; ++e) {
    float qv = As[e][r];
    const float4* tr = (const float4*)&Bs[e][d0];
    #pragma unroll
    for (int q4 = 0; q4 < 4; ++q4) {
      float4 tv = tr[q4];
      acc[q4*4+0] += qv * tv.x; acc[q4*4+1] += qv * tv.y;
      acc[q4*4+2] += qv * tv.z; acc[q4*4+3] += qv * tv.w;
    }
  }
  #pragma unroll
  for (int q = 0; q < 16; ++q) acc[q] *= 0.125f;
  // softmax over row r (4 lanes per row)
  float mx = acc[0];
  #pragma unroll
  for (int q = 1; q < 16; ++q) mx = fmaxf(mx, acc[q]);
  mx = fmaxf(mx, __shfl_xor(mx, 1));
  mx = fmaxf(mx, __shfl_xor(mx, 2));
  float s = 0.f;
  #pragma unroll
  for (int q = 0; q < 16; ++q) { acc[q] = expf(acc[q] - mx); s += acc[q]; }
  s += __shfl_xor(s, 1);
  s += __shfl_xor(s, 2);
  float inv = 1.f / s;
  #pragma unroll
  for (int q = 0; q < 16; ++q) acc[q] *= inv;
  __syncthreads();   // all reads of As(Wq)/Bs done
  #pragma unroll
  for (int q = 0; q < 16; ++q) Gs[r][d0 + q] = acc[q];  // Gs := att
  #pragma unroll
  for (int p = 0; p < 16; ++p) {
    int e = t + p * 256;
    As[e >> 6][e & 63] = Wv[e];
  }
  __syncthreads();
  // M = Wv @ att
  #pragma unroll
  for (int q = 0; q < 16; ++q) acc[q] = 0.f;
  #pragma unroll 1
  for (int e = 0; e < 64; ++e) {
    float wv = As[r][e];
    const float4* ar = (const float4*)&Gs[e][d0];
    #pragma unroll
    for (int q4 = 0; q4 < 4; ++q4) {
      float4 av = ar[q4];
      acc[q4*4+0] += wv * av.x; acc[q4*4+1] += wv * av.y;
      acc[q4*4+2] += wv * av.z; acc[q4*4+3] += wv * av.w;
    }
  }
  #pragma unroll
  for (int q = 0; q < 16; ++q)
    Mout[(size_t)blk * 4096 + r * 64 + d0 + q] = acc[q];
}

// ---------------- K5: fused W-axis IDWT + channel mix -> lo, hi ----------------
__global__ __launch_bounds__(512) void k_wmerge(const float* __restrict__ mp,
                                                const float* __restrict__ M,
                                                float* __restrict__ lo,
                                                float* __restrict__ hi) {
  int b = blockIdx.x >> 7;
  int h = blockIdx.x & 127;
  __shared__ float mps[128][65];
  __shared__ float Ms[4][64][64];
  int t = threadIdx.x;
  // stage mp row [128][64]
  const float* mrow = mp + (size_t)(b * 128 + h) * (WP * NC);
  #pragma unroll
  for (int i = 0; i < 16; ++i) {
    int e = t + i * 512;
    mps[e >> 6][e & 63] = mrow[e];
  }
  // stage M0..M3 for batch b
  #pragma unroll
  for (int i = 0; i < 32; ++i) {
    int e = t + i * 512;           // 0..16383
    int mat = e >> 12;
    Ms[mat][(e >> 6) & 63][e & 63] = M[((size_t)(mat * 8 + b) << 12) + (e & 4095)];
  }
  __syncthreads();
  int half = t >> 8;       // 0 -> lo, 1 -> hi
  int n    = t & 255;
  int par  = n & 1;
  int mj[4]; float cl[4], cg[4];
  #pragma unroll
  for (int j = 0; j < 4; ++j) {
    mj[j] = ((n >> 1) - j) & 127;
    cl[j] = c_h[par + 2 * j];
    cg[j] = c_g[par + 2 * j];
  }
  const int ma = half * 2, mb = half * 2 + 1;
  float acc[64];
  #pragma unroll
  for (int q = 0; q < 64; ++q) acc[q] = 0.f;
  #pragma unroll 1
  for (int a_ = 0; a_ < 64; ++a_) {
    float v0 = mps[mj[0]][a_], v1 = mps[mj[1]][a_];
    float v2 = mps[mj[2]][a_], v3 = mps[mj[3]][a_];
    float u0 = cl[0]*v0 + cl[1]*v1 + cl[2]*v2 + cl[3]*v3;
    float u1 = cg[0]*v0 + cg[1]*v1 + cg[2]*v2 + cg[3]*v3;
    const float4* r0 = (const float4*)Ms[ma][a_];
    const float4* r1 = (const float4*)Ms[mb][a_];
    #pragma unroll
    for (int q = 0; q < 16; ++q) {
      float4 w0 = r0[q], w1 = r1[q];
      acc[4*q+0] += u0*w0.x + u1*w1.x;
      acc[4*q+1] += u0*w0.y + u1*w1.y;
      acc[4*q+2] += u0*w0.z + u1*w1.z;
      acc[4*q+3] += u0*w0.w + u1*w1.w;
    }
  }
  float* dst = (half ? hi : lo) + ((size_t)(b * 128 + h) * 256 + n) * NC;
  #pragma unroll
  for (int q = 0; q < 16; ++q)
    ((float4*)dst)[q] = make_float4(acc[4*q+0], acc[4*q+1], acc[4*q+2], acc[4*q+3]);
}

// ---------------- K6: depthwise conv + H-axis IDWT -> x (= path_a+path_b) ----------------
__global__ __launch_bounds__(512) void k_convmerge(const float* __restrict__ img,
                                                   const float* __restrict__ ker,
                                                   const float* __restrict__ lo,
                                                   const float* __restrict__ hi,
                                                   float* __restrict__ x) {
  int b = blockIdx.x >> 7;
  int r = blockIdx.x & 127;      // output rows 2r, 2r+1
  __shared__ float ks[49][64];
  int t = threadIdx.x;
  #pragma unroll
  for (int i = 0; i < 7; ++i) {
    int e = t + i * 512;
    if (e < 3136) ks[e >> 6][e & 63] = ker[e];
  }
  __syncthreads();
  int c = t & 63;
  int s = t >> 6;        // 8 strips of 32 cols
  int w0 = s * 32;
  #pragma unroll 1
  for (int nn = 0; nn < 2; ++nn) {
    int n = 2 * r + nn;
    float acc[32];
    #pragma unroll
    for (int q = 0; q < 32; ++q) acc[q] = 0.f;
    // depthwise conv, SAME zero padding
    #pragma unroll 1
    for (int dy = 0; dy < 7; ++dy) {
      int row = n - 3 + dy;
      if (row < 0 || row >= NH) continue;
      const float* ibase = img + ((size_t)(b * NH + row) * NW) * NC + c;
      float win[38];
      #pragma unroll
      for (int i2 = 0; i2 < 38; ++i2) {
        int col = w0 - 3 + i2;
        win[i2] = (col >= 0 && col < NW) ? ibase[(size_t)col * NC] : 0.f;
      }
      #pragma unroll
      for (int dx = 0; dx < 7; ++dx) {
        float kv = ks[dy * 7 + dx][c];
        #pragma unroll
        for (int ww = 0; ww < 32; ++ww) acc[ww] += kv * win[ww + dx];
      }
    }
    // H-merge: rows (r-j)&127 of lo/hi
    int par = n & 1;
    #pragma unroll
    for (int j = 0; j < 4; ++j) {
      int mrow = (r - j) & 127;
      float clv = c_h[par + 2 * j];
      float cgv = c_g[par + 2 * j];
      const float* lb = lo + ((size_t)(b * 128 + mrow) * 256 + w0) * NC + c;
      const float* hb = hi + ((size_t)(b * 128 + mrow) * 256 + w0) * NC + c;
      #pragma unroll
      for (int ww = 0; ww < 32; ++ww)
        acc[ww] += clv * lb[(size_t)ww * NC] + cgv * hb[(size_t)ww * NC];
    }
    float* xb = x + ((size_t)(b * NH + n) * NW + w0) * NC + c;
    #pragma unroll
    for (int ww = 0; ww < 32; ++ww) xb[(size_t)ww * NC] = acc[ww];
  }
}

// ---------------- K7: in-place LayerNorm + MLP (64 -> 256 GELU -> 64) ----------------
// 256 threads / 1 pixel each; hidden dim processed in 2 chunks of 128 so LDS
// stays at 64 KB and per-thread state (xv[64]+o[64]) stays in VGPRs.
__global__ __launch_bounds__(256, 1) void k_mlp(const float* __restrict__ xin,
                                                const float* __restrict__ gamma,
                                                const float* __restrict__ beta,
                                                const float* __restrict__ W1,
                                                const float* __restrict__ b1,
                                                const float* __restrict__ W2,
                                                const float* __restrict__ b2,
                                                float* __restrict__ out) {
  __shared__ float W1s[64][128];   // W1[:, half*128 : half*128+128]
  __shared__ float W2s[128][64];   // W2[half*128 : half*128+128, :]
  int t = threadIdx.x;
  size_t pix = (size_t)blockIdx.x * 256 + t;
  const float* xp = xin + pix * 64;
  float xv[64];
  #pragma unroll
  for (int q = 0; q < 16; ++q) {
    float4 v = ((const float4*)xp)[q];
    xv[4*q+0] = v.x; xv[4*q+1] = v.y; xv[4*q+2] = v.z; xv[4*q+3] = v.w;
  }
  float mu = 0.f;
  #pragma unroll
  for (int i = 0; i < 64; ++i) mu += xv[i];
  mu *= 0.015625f;
  float var = 0.f;
  #pragma unroll
  for (int i = 0; i < 64; ++i) { float d = xv[i] - mu; var += d * d; }
  var *= 0.015625f;
  float rs = rsqrtf(var + 1e-3f);
  #pragma unroll
  for (int i = 0; i < 64; ++i) xv[i] = (xv[i] - mu) * rs * gamma[i] + beta[i];
  float o[64];
  #pragma unroll
  for (int d = 0; d < 64; ++d) o[d] = b2[d];
  #pragma unroll 1
  for (int half = 0; half < 2; ++half) {
    __syncthreads();   // previous chunk fully consumed before overwrite
    #pragma unroll
    for (int i = 0; i < 32; ++i) {
      int e = t + i * 256;   // 0..8191
      W1s[e >> 7][e & 127] = W1[(size_t)(e >> 7) * 256 + half * 128 + (e & 127)];
      ((float*)W2s)[e] = W2[half * 8192 + e];
    }
    __syncthreads();
    #pragma unroll 1
    for (int jc = 0; jc < 128; jc += 8) {
      float hj[8];
      #pragma unroll
      for (int q = 0; q < 8; ++q) hj[q] = b1[half * 128 + jc + q];
      #pragma unroll
      for (int e = 0; e < 64; ++e) {
        float xe = xv[e];
        const float4* wr = (const float4*)&W1s[e][jc];
        float4 w0 = wr[0], w1 = wr[1];
        hj[0] += xe * w0.x; hj[1] += xe * w0.y; hj[2] += xe * w0.z; hj[3] += xe * w0.w;
        hj[4] += xe * w1.x; hj[5] += xe * w1.y; hj[6] += xe * w1.z; hj[7] += xe * w1.w;
      }
      #pragma unroll
      for (int q = 0; q < 8; ++q) {
        float hv = hj[q];
        float gl = 0.5f * hv * (1.f + erff(hv * 0.70710678118654752f));
        const float4* w2r = (const float4*)&W2s[jc + q][0];
        #pragma unroll
        for (int d4 = 0; d4 < 16; ++d4) {
          float4 wv = w2r[d4];
          o[4*d4+0] += gl * wv.x; o[4*d4+1] += gl * wv.y;
          o[4*d4+2] += gl * wv.z; o[4*d4+3] += gl * wv.w;
        }
      }
    }
  }
  float* op = out + pix * 64;
  #pragma unroll
  for (int q = 0; q < 16; ++q)
    ((float4*)op)[q] = make_float4(o[4*q+0], o[4*q+1], o[4*q+2], o[4*q+3]);
}

extern "C" void kernel_launch(void* const* d_in, const int* in_sizes, int n_in,
                              void* d_out, int out_size, void* d_ws, size_t ws_size,
                              hipStream_t stream) {
  const float* images = (const float*)d_in[0];
  const float* dwk    = (const float*)d_in[1];
  const float* Wv     = (const float*)d_in[2];
  const float* Wq     = (const float*)d_in[3];
  const float* Wk     = (const float*)d_in[4];
  const float* gamma  = (const float*)d_in[5];
  const float* beta   = (const float*)d_in[6];
  const float* W1     = (const float*)d_in[7];
  const float* b1     = (const float*)d_in[8];
  const float* W2     = (const float*)d_in[9];
  const float* b2     = (const float*)d_in[10];
  float* out = (float*)d_out;
  float* ws  = (float*)d_ws;

  float* mp    = ws;                  // 8,388,608
  float* bands = ws + 8388608;        // 8,388,608 (4 bands)
  float* G     = ws + 16777216;       // 131,072
  float* Mm    = ws + 16908288;       // 131,072
  float* lo    = ws + 17039360;       // 16,777,216
  float* hi    = ws + 33816576;       // 16,777,216
  float* tLo   = lo;                  // DWT temps alias lo/hi (dead before overwrite)
  float* tHi   = hi;

  k_maxpool<<<32768, 256, 0, stream>>>(images, mp);
  k_dwt_h<<<16384, 256, 0, stream>>>(mp, tLo, tHi);
  k_dwt_w<<<8192, 256, 0, stream>>>(tLo, tHi, bands);
  k_gram<<<32, 256, 0, stream>>>(bands, G);
  k_att<<<32, 256, 0, stream>>>(G, Wq, Wk, Wv, Mm);
  k_wmerge<<<1024, 512, 0, stream>>>(mp, Mm, lo, hi);
  k_convmerge<<<1024, 512, 0, stream>>>(images, dwk, lo, hi, out);
  k_mlp<<<2048, 256, 0, stream>>>(out, gamma, beta, W1, b1, W2, b2, out);
}

// Round 6
// 1503.701 us; speedup vs baseline: 23.0566x; 9.8798x over previous
//
#include <hip/hip_runtime.h>
#include <math.h>

#define NB 8
#define NH 256
#define NW 256
#define NC 64
#define HP 128
#define WP 128

typedef short bf16x8 __attribute__((ext_vector_type(8)));
typedef float f32x4 __attribute__((ext_vector_type(4)));

__device__ inline unsigned short f2b(float f) {
  unsigned u = __float_as_uint(f);
  u += 0x7fffu + ((u >> 16) & 1u);
  return (unsigned short)(u >> 16);
}

// db4 analysis filters (lo = c_h, hi = c_g with g[k] = (-1)^k h[7-k])
__constant__ float c_h[8] = {
  -0.010597401784997278f, 0.032883011666982945f, 0.030841381835986965f,
  -0.18703481171888114f, -0.02798376941698385f, 0.6308807679295904f,
   0.7148465705525415f,   0.23037781330885523f};
__constant__ float c_g[8] = {
   0.23037781330885523f, -0.7148465705525415f,  0.6308807679295904f,
   0.02798376941698385f, -0.18703481171888114f, -0.030841381835986965f,
   0.032883011666982945f, 0.010597401784997278f};

// ---------------- K0: transpose + bf16-cast MLP weights ----------------
__global__ __launch_bounds__(256) void k_prep(const float* __restrict__ W1,
                                              const float* __restrict__ W2,
                                              unsigned short* __restrict__ w1t,
                                              unsigned short* __restrict__ w2t) {
  int t = threadIdx.x;
  for (int e = t; e < 16384; e += 256) {      // W1[k][n], k<64, n<256 -> w1t[n][k]
    w1t[(e & 255) * 64 + (e >> 8)] = f2b(W1[e]);
  }
  for (int e = t; e < 16384; e += 256) {      // W2[k][n], k<256, n<64 -> w2t[n][k]
    w2t[(e & 63) * 256 + (e >> 6)] = f2b(W2[e]);
  }
}

// ---------------- K1: 2x2 maxpool ----------------
__global__ __launch_bounds__(256) void k_maxpool(const float* __restrict__ img,
                                                 float* __restrict__ mp) {
  int idx = blockIdx.x * 256 + threadIdx.x;   // 8*128*128*64 = 8388608
  int c  = idx & 63;
  int wp = (idx >> 6) & 127;
  int hp = (idx >> 13) & 127;
  int b  = idx >> 20;
  const float* p = img + (((size_t)b * NH + 2 * hp) * NW + 2 * wp) * NC + c;
  float v0 = p[0], v1 = p[NC], v2 = p[(size_t)NW * NC], v3 = p[(size_t)NW * NC + NC];
  mp[idx] = fmaxf(fmaxf(v0, v1), fmaxf(v2, v3));
}

// ---------------- K2a: DWT along H ----------------
__global__ __launch_bounds__(256) void k_dwt_h(const float* __restrict__ mp,
                                               float* __restrict__ tLo,
                                               float* __restrict__ tHi) {
  int idx = blockIdx.x * 256 + threadIdx.x;   // 8*64*128*64 = 4194304
  int c = idx & 63;
  int w = (idx >> 6) & 127;
  int m = (idx >> 13) & 63;
  int b = idx >> 19;
  const float* base = mp + (size_t)b * (HP * WP * NC) + (size_t)w * NC + c;
  float lo = 0.f, hi = 0.f;
  #pragma unroll
  for (int k = 0; k < 8; ++k) {
    int r = (2 * m + k) & 127;
    float v = base[(size_t)r * (WP * NC)];
    lo += c_h[k] * v;
    hi += c_g[k] * v;
  }
  tLo[idx] = lo;   // [b][m][w][c]
  tHi[idx] = hi;
}

// ---------------- K2b: DWT along W -> 4 bands ----------------
__global__ __launch_bounds__(256) void k_dwt_w(const float* __restrict__ tLo,
                                               const float* __restrict__ tHi,
                                               float* __restrict__ bands) {
  int idx = blockIdx.x * 256 + threadIdx.x;   // 8*64*64*64 = 2097152
  int c = idx & 63;
  int u = (idx >> 6) & 63;
  int m = (idx >> 12) & 63;
  int b = idx >> 18;
  size_t rowbase = ((size_t)(b * 64 + m) * 128) * NC + c;
  float ll = 0.f, lh = 0.f, hl = 0.f, hh = 0.f;
  #pragma unroll
  for (int k = 0; k < 8; ++k) {
    int w = (2 * u + k) & 127;
    float a = tLo[rowbase + (size_t)w * NC];
    float d = tHi[rowbase + (size_t)w * NC];
    ll += c_h[k] * a;  lh += c_g[k] * a;
    hl += c_h[k] * d;  hh += c_g[k] * d;
  }
  const size_t bs = 2097152;  // 8*64*64*64
  bands[0 * bs + idx] = ll;
  bands[1 * bs + idx] = lh;
  bands[2 * bs + idx] = hl;
  bands[3 * bs + idx] = hh;
}

// ---------------- K3: per-(band,batch) Gram G = fb^T fb ----------------
__global__ __launch_bounds__(256) void k_gram(const float* __restrict__ bands,
                                              float* __restrict__ G) {
  int blk = blockIdx.x;                        // = band*8 + b, 32 blocks
  const float* fb = bands + (size_t)blk * 262144;  // [4096][64]
  __shared__ float fbs[64][64];
  int t = threadIdx.x;
  int c2 = t & 63;
  int a  = t >> 6;        // 0..3 (wave id)
  float acc[16];
  #pragma unroll
  for (int q = 0; q < 16; ++q) acc[q] = 0.f;
  #pragma unroll 1
  for (int chunk = 0; chunk < 64; ++chunk) {
    #pragma unroll
    for (int i = 0; i < 16; ++i) {
      int e = t + i * 256;
      fbs[e >> 6][e & 63] = fb[(size_t)chunk * 4096 + e];
    }
    __syncthreads();
    #pragma unroll 1
    for (int rr = 0; rr < 64; ++rr) {
      float v2 = fbs[rr][c2];
      const float4* row4 = (const float4*)&fbs[rr][a * 16];
      #pragma unroll
      for (int q4 = 0; q4 < 4; ++q4) {
        float4 va = row4[q4];
        acc[q4 * 4 + 0] += va.x * v2;
        acc[q4 * 4 + 1] += va.y * v2;
        acc[q4 * 4 + 2] += va.z * v2;
        acc[q4 * 4 + 3] += va.w * v2;
      }
    }
    __syncthreads();
  }
  #pragma unroll
  for (int q = 0; q < 16; ++q)
    G[(size_t)blk * 4096 + (a * 16 + q) * 64 + c2] = acc[q];
}

// ---------------- K4: att = softmax(Wq^T G Wk / 8); M = Wv @ att ----------------
__global__ __launch_bounds__(256) void k_att(const float* __restrict__ G,
                                             const float* __restrict__ Wq,
                                             const float* __restrict__ Wk,
                                             const float* __restrict__ Wv,
                                             float* __restrict__ Mout) {
  int blk = blockIdx.x;        // band*8 + b
  int band = blk >> 3;
  __shared__ float Gs[64][68];
  __shared__ float As[64][68];
  __shared__ float Bs[64][68];
  int t = threadIdx.x;
  #pragma unroll
  for (int p = 0; p < 16; ++p) {
    int e = t + p * 256;
    Gs[e >> 6][e & 63] = G[(size_t)blk * 4096 + e];
    As[e >> 6][e & 63] = Wk[(size_t)band * 4096 + e];
  }
  __syncthreads();
  int r  = t >> 2;
  int d0 = (t & 3) << 4;
  float acc[16];
  // T1 = G @ Wk
  #pragma unroll
  for (int q = 0; q < 16; ++q) acc[q] = 0.f;
  #pragma unroll 1
  for (int e = 0; e < 64; ++e) {
    float gv = Gs[r][e];
    const float4* wr = (const float4*)&As[e][d0];
    #pragma unroll
    for (int q4 = 0; q4 < 4; ++q4) {
      float4 wv = wr[q4];
      acc[q4*4+0] += gv * wv.x; acc[q4*4+1] += gv * wv.y;
      acc[q4*4+2] += gv * wv.z; acc[q4*4+3] += gv * wv.w;
    }
  }
  __syncthreads();   // all reads of As(Wk)/Gs done
  #pragma unroll
  for (int q = 0; q < 16; ++q) Bs[r][d0 + q] = acc[q];
  #pragma unroll
  for (int p = 0; p < 16; ++p) {
    int e = t + p * 256;
    As[e >> 6][e & 63] = Wq[(size_t)band * 4096 + e];
  }
  __syncthreads();
  // att = Wq^T T1 / 8
  #pragma unroll
  for (int q = 0; q < 16; ++q) acc[q] = 0.f;
  #pragma unroll 1
  for (int e = 0; e < 64; ++e) {
    float qv = As[e][r];
    const float4* tr = (const float4*)&Bs[e][d0];
    #pragma unroll
    for (int q4 = 0; q4 < 4; ++q4) {
      float4 tv = tr[q4];
      acc[q4*4+0] += qv * tv.x; acc[q4*4+1] += qv * tv.y;
      acc[q4*4+2] += qv * tv.z; acc[q4*4+3] += qv * tv.w;
    }
  }
  #pragma unroll
  for (int q = 0; q < 16; ++q) acc[q] *= 0.125f;
  // softmax over row r (4 lanes per row)
  float mx = acc[0];
  #pragma unroll
  for (int q = 1; q < 16; ++q) mx = fmaxf(mx, acc[q]);
  mx = fmaxf(mx, __shfl_xor(mx, 1));
  mx = fmaxf(mx, __shfl_xor(mx, 2));
  float s = 0.f;
  #pragma unroll
  for (int q = 0; q < 16; ++q) { acc[q] = expf(acc[q] - mx); s += acc[q]; }
  s += __shfl_xor(s, 1);
  s += __shfl_xor(s, 2);
  float inv = 1.f / s;
  #pragma unroll
  for (int q = 0; q < 16; ++q) acc[q] *= inv;
  __syncthreads();   // all reads of As(Wq)/Bs done
  #pragma unroll
  for (int q = 0; q < 16; ++q) Gs[r][d0 + q] = acc[q];  // Gs := att
  #pragma unroll
  for (int p = 0; p < 16; ++p) {
    int e = t + p * 256;
    As[e >> 6][e & 63] = Wv[e];
  }
  __syncthreads();
  // M = Wv @ att
  #pragma unroll
  for (int q = 0; q < 16; ++q) acc[q] = 0.f;
  #pragma unroll 1
  for (int e = 0; e < 64; ++e) {
    float wv = As[r][e];
    const float4* ar = (const float4*)&Gs[e][d0];
    #pragma unroll
    for (int q4 = 0; q4 < 4; ++q4) {
      float4 av = ar[q4];
      acc[q4*4+0] += wv * av.x; acc[q4*4+1] += wv * av.y;
      acc[q4*4+2] += wv * av.z; acc[q4*4+3] += wv * av.w;
    }
  }
  #pragma unroll
  for (int q = 0; q < 16; ++q)
    Mout[(size_t)blk * 4096 + r * 64 + d0 + q] = acc[q];
}

// ---------------- K5: fused W-axis IDWT + channel mix -> lo, hi ----------------
__global__ __launch_bounds__(512) void k_wmerge(const float* __restrict__ mp,
                                                const float* __restrict__ M,
                                                float* __restrict__ lo,
                                                float* __restrict__ hi) {
  int b = blockIdx.x >> 7;
  int h = blockIdx.x & 127;
  __shared__ float mps[128][65];
  __shared__ float Ms[4][64][64];
  int t = threadIdx.x;
  // stage mp row [128][64]
  const float* mrow = mp + (size_t)(b * 128 + h) * (WP * NC);
  #pragma unroll
  for (int i = 0; i < 16; ++i) {
    int e = t + i * 512;
    mps[e >> 6][e & 63] = mrow[e];
  }
  // stage M0..M3 for batch b
  #pragma unroll
  for (int i = 0; i < 32; ++i) {
    int e = t + i * 512;           // 0..16383
    int mat = e >> 12;
    Ms[mat][(e >> 6) & 63][e & 63] = M[((size_t)(mat * 8 + b) << 12) + (e & 4095)];
  }
  __syncthreads();
  int half = t >> 8;       // 0 -> lo, 1 -> hi
  int n    = t & 255;
  int par  = n & 1;
  int mj[4]; float cl[4], cg[4];
  #pragma unroll
  for (int j = 0; j < 4; ++j) {
    mj[j] = ((n >> 1) - j) & 127;
    cl[j] = c_h[par + 2 * j];
    cg[j] = c_g[par + 2 * j];
  }
  const int ma = half * 2, mb = half * 2 + 1;
  float acc[64];
  #pragma unroll
  for (int q = 0; q < 64; ++q) acc[q] = 0.f;
  #pragma unroll 1
  for (int a_ = 0; a_ < 64; ++a_) {
    float v0 = mps[mj[0]][a_], v1 = mps[mj[1]][a_];
    float v2 = mps[mj[2]][a_], v3 = mps[mj[3]][a_];
    float u0 = cl[0]*v0 + cl[1]*v1 + cl[2]*v2 + cl[3]*v3;
    float u1 = cg[0]*v0 + cg[1]*v1 + cg[2]*v2 + cg[3]*v3;
    const float4* r0 = (const float4*)Ms[ma][a_];
    const float4* r1 = (const float4*)Ms[mb][a_];
    #pragma unroll
    for (int q = 0; q < 16; ++q) {
      float4 w0 = r0[q], w1 = r1[q];
      acc[4*q+0] += u0*w0.x + u1*w1.x;
      acc[4*q+1] += u0*w0.y + u1*w1.y;
      acc[4*q+2] += u0*w0.z + u1*w1.z;
      acc[4*q+3] += u0*w0.w + u1*w1.w;
    }
  }
  float* dst = (half ? hi : lo) + ((size_t)(b * 128 + h) * 256 + n) * NC;
  #pragma unroll
  for (int q = 0; q < 16; ++q)
    ((float4*)dst)[q] = make_float4(acc[4*q+0], acc[4*q+1], acc[4*q+2], acc[4*q+3]);
}

// ---------------- K6: depthwise conv + H-axis IDWT -> x (= path_a+path_b) ----------------
__global__ __launch_bounds__(512) void k_convmerge(const float* __restrict__ img,
                                                   const float* __restrict__ ker,
                                                   const float* __restrict__ lo,
                                                   const float* __restrict__ hi,
                                                   float* __restrict__ x) {
  int b = blockIdx.x >> 7;
  int r = blockIdx.x & 127;      // output rows 2r, 2r+1
  __shared__ float ks[49][64];
  int t = threadIdx.x;
  #pragma unroll
  for (int i = 0; i < 7; ++i) {
    int e = t + i * 512;
    if (e < 3136) ks[e >> 6][e & 63] = ker[e];
  }
  __syncthreads();
  int c = t & 63;
  int s = t >> 6;        // 8 strips of 32 cols
  int w0 = s * 32;
  #pragma unroll 1
  for (int nn = 0; nn < 2; ++nn) {
    int n = 2 * r + nn;
    float acc[32];
    #pragma unroll
    for (int q = 0; q < 32; ++q) acc[q] = 0.f;
    // depthwise conv, SAME zero padding
    #pragma unroll 1
    for (int dy = 0; dy < 7; ++dy) {
      int row = n - 3 + dy;
      if (row < 0 || row >= NH) continue;
      const float* ibase = img + ((size_t)(b * NH + row) * NW) * NC + c;
      float win[38];
      #pragma unroll
      for (int i2 = 0; i2 < 38; ++i2) {
        int col = w0 - 3 + i2;
        win[i2] = (col >= 0 && col < NW) ? ibase[(size_t)col * NC] : 0.f;
      }
      #pragma unroll
      for (int dx = 0; dx < 7; ++dx) {
        float kv = ks[dy * 7 + dx][c];
        #pragma unroll
        for (int ww = 0; ww < 32; ++ww) acc[ww] += kv * win[ww + dx];
      }
    }
    // H-merge: rows (r-j)&127 of lo/hi
    int par = n & 1;
    #pragma unroll
    for (int j = 0; j < 4; ++j) {
      int mrow = (r - j) & 127;
      float clv = c_h[par + 2 * j];
      float cgv = c_g[par + 2 * j];
      const float* lb = lo + ((size_t)(b * 128 + mrow) * 256 + w0) * NC + c;
      const float* hb = hi + ((size_t)(b * 128 + mrow) * 256 + w0) * NC + c;
      #pragma unroll
      for (int ww = 0; ww < 32; ++ww)
        acc[ww] += clv * lb[(size_t)ww * NC] + cgv * hb[(size_t)ww * NC];
    }
    float* xb = x + ((size_t)(b * NH + n) * NW + w0) * NC + c;
    #pragma unroll
    for (int ww = 0; ww < 32; ++ww) xb[(size_t)ww * NC] = acc[ww];
  }
}

// ---------------- K7: LayerNorm + MLP via bf16 MFMA ----------------
// 512 thr / 128 pixels per block; hidden in 4 quarters of 64.
// LDS: x[128][72] + h[128][72] + W1q[64][72] + W2q[64][72] bf16 = 55296 B.
__global__ __launch_bounds__(512, 1) void k_mlp(const float* __restrict__ xin,
                                                const float* __restrict__ gamma,
                                                const float* __restrict__ beta,
                                                const unsigned short* __restrict__ w1t,
                                                const float* __restrict__ b1,
                                                const unsigned short* __restrict__ w2t,
                                                const float* __restrict__ b2,
                                                float* __restrict__ out) {
  __shared__ unsigned short x_s[128 * 72];
  __shared__ unsigned short h_s[128 * 72];
  __shared__ unsigned short w1_s[64 * 72];
  __shared__ unsigned short w2_s[64 * 72];
  int t = threadIdx.x;
  size_t pix0 = (size_t)blockIdx.x * 128;

  // ---- LN: 4 threads per pixel, 16 channels each ----
  {
    int pj = t >> 2, ch0 = (t & 3) * 16;
    const float* xp = xin + (pix0 + pj) * 64 + ch0;
    float xv[16];
    #pragma unroll
    for (int q = 0; q < 4; ++q) {
      float4 v = ((const float4*)xp)[q];
      xv[4*q+0] = v.x; xv[4*q+1] = v.y; xv[4*q+2] = v.z; xv[4*q+3] = v.w;
    }
    float sp = 0.f;
    #pragma unroll
    for (int i = 0; i < 16; ++i) sp += xv[i];
    sp += __shfl_xor(sp, 1);
    sp += __shfl_xor(sp, 2);
    float mu = sp * 0.015625f;
    float vp = 0.f;
    #pragma unroll
    for (int i = 0; i < 16; ++i) { float d = xv[i] - mu; vp += d * d; }
    vp += __shfl_xor(vp, 1);
    vp += __shfl_xor(vp, 2);
    float rs = rsqrtf(vp * 0.015625f + 1e-3f);
    const float4* gp = (const float4*)(gamma + ch0);
    const float4* bp = (const float4*)(beta + ch0);
    bf16x8 o0, o1;
    #pragma unroll
    for (int q = 0; q < 4; ++q) {
      float4 g = gp[q], bb = bp[q];
      unsigned short e0 = f2b((xv[4*q+0] - mu) * rs * g.x + bb.x);
      unsigned short e1 = f2b((xv[4*q+1] - mu) * rs * g.y + bb.y);
      unsigned short e2 = f2b((xv[4*q+2] - mu) * rs * g.z + bb.z);
      unsigned short e3 = f2b((xv[4*q+3] - mu) * rs * g.w + bb.w);
      if (q < 2) { o0[4*q+0]=(short)e0; o0[4*q+1]=(short)e1; o0[4*q+2]=(short)e2; o0[4*q+3]=(short)e3; }
      else { o1[4*(q-2)+0]=(short)e0; o1[4*(q-2)+1]=(short)e1; o1[4*(q-2)+2]=(short)e2; o1[4*(q-2)+3]=(short)e3; }
    }
    *(bf16x8*)&x_s[pj * 72 + ch0] = o0;
    *(bf16x8*)&x_s[pj * 72 + ch0 + 8] = o1;
  }

  const int w  = t >> 6;        // wave 0..7 -> pixels 16w..16w+15
  const int l  = t & 63;
  const int ar = l & 15;
  const int ko = (l >> 4) * 8;
  const int sn = t >> 3;        // staging: row 0..63
  const int sk = (t & 7) * 8;   // staging: col 0..56

  f32x4 acc2[4];
  #pragma unroll
  for (int nt = 0; nt < 4; ++nt) acc2[nt] = (f32x4){0.f, 0.f, 0.f, 0.f};

  #pragma unroll 1
  for (int q = 0; q < 4; ++q) {
    __syncthreads();   // protect w1_s/w2_s/h_s overwrite vs previous reads (and x_s writes at q=0)
    *(bf16x8*)&w1_s[sn * 72 + sk] = *(const bf16x8*)&w1t[(q * 64 + sn) * 64 + sk];
    *(bf16x8*)&w2_s[sn * 72 + sk] = *(const bf16x8*)&w2t[sn * 256 + q * 64 + sk];
    __syncthreads();
    // ---- GEMM1 quarter: h[128][64] = x[128][64] @ W1q[64][64], +b1, GELU ----
    const unsigned short* abase = &x_s[(w * 16 + ar) * 72];
    #pragma unroll
    for (int nt = 0; nt < 4; ++nt) {
      f32x4 acc = (f32x4){0.f, 0.f, 0.f, 0.f};
      const unsigned short* bbase = &w1_s[(nt * 16 + ar) * 72];
      acc = __builtin_amdgcn_mfma_f32_16x16x32_bf16(*(const bf16x8*)(abase + ko),
                                                    *(const bf16x8*)(bbase + ko), acc, 0, 0, 0);
      acc = __builtin_amdgcn_mfma_f32_16x16x32_bf16(*(const bf16x8*)(abase + 32 + ko),
                                                    *(const bf16x8*)(bbase + 32 + ko), acc, 0, 0, 0);
      int col = nt * 16 + ar;
      float bv = b1[q * 64 + col];
      #pragma unroll
      for (int r = 0; r < 4; ++r) {
        int pr = w * 16 + (l >> 4) * 4 + r;
        float hv = acc[r] + bv;
        float gl = 0.5f * hv * (1.f + erff(hv * 0.70710678118654752f));
        h_s[pr * 72 + col] = f2b(gl);
      }
    }
    __syncthreads();
    // ---- GEMM2 partial: out[128][64] += h[128][64] @ W2q[64][64] ----
    const unsigned short* a2base = &h_s[(w * 16 + ar) * 72];
    #pragma unroll
    for (int nt = 0; nt < 4; ++nt) {
      const unsigned short* b2base = &w2_s[(nt * 16 + ar) * 72];
      acc2[nt] = __builtin_amdgcn_mfma_f32_16x16x32_bf16(*(const bf16x8*)(a2base + ko),
                                                         *(const bf16x8*)(b2base + ko), acc2[nt], 0, 0, 0);
      acc2[nt] = __builtin_amdgcn_mfma_f32_16x16x32_bf16(*(const bf16x8*)(a2base + 32 + ko),
                                                         *(const bf16x8*)(b2base + 32 + ko), acc2[nt], 0, 0, 0);
    }
  }

  // ---- epilogue: +b2, store ----
  #pragma unroll
  for (int nt = 0; nt < 4; ++nt) {
    int col = nt * 16 + ar;
    float bb = b2[col];
    #pragma unroll
    for (int r = 0; r < 4; ++r) {
      int pr = w * 16 + (l >> 4) * 4 + r;
      out[(pix0 + pr) * 64 + col] = acc2[nt][r] + bb;
    }
  }
}

extern "C" void kernel_launch(void* const* d_in, const int* in_sizes, int n_in,
                              void* d_out, int out_size, void* d_ws, size_t ws_size,
                              hipStream_t stream) {
  const float* images = (const float*)d_in[0];
  const float* dwk    = (const float*)d_in[1];
  const float* Wv     = (const float*)d_in[2];
  const float* Wq     = (const float*)d_in[3];
  const float* Wk     = (const float*)d_in[4];
  const float* gamma  = (const float*)d_in[5];
  const float* beta   = (const float*)d_in[6];
  const float* W1     = (const float*)d_in[7];
  const float* b1     = (const float*)d_in[8];
  const float* W2     = (const float*)d_in[9];
  const float* b2     = (const float*)d_in[10];
  float* out = (float*)d_out;
  float* ws  = (float*)d_ws;

  float* mp    = ws;                  // 8,388,608
  float* bands = ws + 8388608;        // 8,388,608 (4 bands)
  float* G     = ws + 16777216;       // 131,072
  float* Mm    = ws + 16908288;       // 131,072
  float* lo    = ws + 17039360;       // 16,777,216
  float* hi    = ws + 33816576;       // 16,777,216
  float* tLo   = lo;                  // DWT temps alias lo/hi (dead before overwrite)
  float* tHi   = hi;
  unsigned short* w1t = (unsigned short*)(ws + 50593792);  // 16384 bf16
  unsigned short* w2t = w1t + 16384;                       // 16384 bf16

  k_prep<<<1, 256, 0, stream>>>(W1, W2, w1t, w2t);
  k_maxpool<<<32768, 256, 0, stream>>>(images, mp);
  k_dwt_h<<<16384, 256, 0, stream>>>(mp, tLo, tHi);
  k_dwt_w<<<8192, 256, 0, stream>>>(tLo, tHi, bands);
  k_gram<<<32, 256, 0, stream>>>(bands, G);
  k_att<<<32, 256, 0, stream>>>(G, Wq, Wk, Wv, Mm);
  k_wmerge<<<1024, 512, 0, stream>>>(mp, Mm, lo, hi);
  k_convmerge<<<1024, 512, 0, stream>>>(images, dwk, lo, hi, out);
  k_mlp<<<4096, 512, 0, stream>>>(out, gamma, beta, w1t, b1, w2t, b2, out);
}

// Round 8
// 1197.337 us; speedup vs baseline: 28.9561x; 1.2559x over previous
//
#include <hip/hip_runtime.h>
#include <math.h>

#define NB 8
#define NH 256
#define NW 256
#define NC 64
#define HP 128
#define WP 128

typedef short bf16x8 __attribute__((ext_vector_type(8)));
typedef float f32x4 __attribute__((ext_vector_type(4)));

__device__ inline unsigned short f2b(float f) {
  unsigned u = __float_as_uint(f);
  u += 0x7fffu + ((u >> 16) & 1u);
  return (unsigned short)(u >> 16);
}

// db4 analysis filters (lo = c_h, hi = c_g with g[k] = (-1)^k h[7-k])
__constant__ float c_h[8] = {
  -0.010597401784997278f, 0.032883011666982945f, 0.030841381835986965f,
  -0.18703481171888114f, -0.02798376941698385f, 0.6308807679295904f,
   0.7148465705525415f,   0.23037781330885523f};
__constant__ float c_g[8] = {
   0.23037781330885523f, -0.7148465705525415f,  0.6308807679295904f,
   0.02798376941698385f, -0.18703481171888114f, -0.030841381835986965f,
   0.032883011666982945f, 0.010597401784997278f};

// ---------------- K0: transpose + bf16-cast MLP weights ----------------
__global__ __launch_bounds__(256) void k_prep(const float* __restrict__ W1,
                                              const float* __restrict__ W2,
                                              unsigned short* __restrict__ w1t,
                                              unsigned short* __restrict__ w2t) {
  int t = threadIdx.x;
  for (int e = t; e < 16384; e += 256) {      // W1[k][n], k<64, n<256 -> w1t[n][k]
    w1t[(e & 255) * 64 + (e >> 8)] = f2b(W1[e]);
  }
  for (int e = t; e < 16384; e += 256) {      // W2[k][n], k<256, n<64 -> w2t[n][k]
    w2t[(e & 63) * 256 + (e >> 6)] = f2b(W2[e]);
  }
}

// ---------------- K1: 2x2 maxpool ----------------
__global__ __launch_bounds__(256) void k_maxpool(const float* __restrict__ img,
                                                 float* __restrict__ mp) {
  int idx = blockIdx.x * 256 + threadIdx.x;   // 8*128*128*64 = 8388608
  int c  = idx & 63;
  int wp = (idx >> 6) & 127;
  int hp = (idx >> 13) & 127;
  int b  = idx >> 20;
  const float* p = img + (((size_t)b * NH + 2 * hp) * NW + 2 * wp) * NC + c;
  float v0 = p[0], v1 = p[NC], v2 = p[(size_t)NW * NC], v3 = p[(size_t)NW * NC + NC];
  mp[idx] = fmaxf(fmaxf(v0, v1), fmaxf(v2, v3));
}

// ---------------- K2a: DWT along H (XCD-chunked swizzle: batch k -> XCD k) ----------------
__global__ __launch_bounds__(256) void k_dwt_h(const float* __restrict__ mp,
                                               float* __restrict__ tLo,
                                               float* __restrict__ tHi) {
  int blk = blockIdx.x;                       // 16384 blocks
  int sw  = (blk & 7) * 2048 + (blk >> 3);    // bijective: 16384 % 8 == 0
  int idx = sw * 256 + threadIdx.x;           // 8*64*128*64 = 4194304
  int c = idx & 63;
  int w = (idx >> 6) & 127;
  int m = (idx >> 13) & 63;
  int b = idx >> 19;
  const float* base = mp + (size_t)b * (HP * WP * NC) + (size_t)w * NC + c;
  float lo = 0.f, hi = 0.f;
  #pragma unroll
  for (int k = 0; k < 8; ++k) {
    int r = (2 * m + k) & 127;
    float v = base[(size_t)r * (WP * NC)];
    lo += c_h[k] * v;
    hi += c_g[k] * v;
  }
  tLo[idx] = lo;   // [b][m][w][c]
  tHi[idx] = hi;
}

// ---------------- K2b: DWT along W -> 4 bands (XCD-chunked swizzle) ----------------
__global__ __launch_bounds__(256) void k_dwt_w(const float* __restrict__ tLo,
                                               const float* __restrict__ tHi,
                                               float* __restrict__ bands) {
  int blk = blockIdx.x;                       // 8192 blocks
  int sw  = (blk & 7) * 1024 + (blk >> 3);
  int idx = sw * 256 + threadIdx.x;           // 8*64*64*64 = 2097152
  int c = idx & 63;
  int u = (idx >> 6) & 63;
  int m = (idx >> 12) & 63;
  int b = idx >> 18;
  size_t rowbase = ((size_t)(b * 64 + m) * 128) * NC + c;
  float ll = 0.f, lh = 0.f, hl = 0.f, hh = 0.f;
  #pragma unroll
  for (int k = 0; k < 8; ++k) {
    int w = (2 * u + k) & 127;
    float a = tLo[rowbase + (size_t)w * NC];
    float d = tHi[rowbase + (size_t)w * NC];
    ll += c_h[k] * a;  lh += c_g[k] * a;
    hl += c_h[k] * d;  hh += c_g[k] * d;
  }
  const size_t bs = 2097152;  // 8*64*64*64
  bands[0 * bs + idx] = ll;
  bands[1 * bs + idx] = lh;
  bands[2 * bs + idx] = hl;
  bands[3 * bs + idx] = hh;
}

// ---------------- K3: per-(band,batch) Gram G = fb^T fb ----------------
__global__ __launch_bounds__(256) void k_gram(const float* __restrict__ bands,
                                              float* __restrict__ G) {
  int blk = blockIdx.x;                        // = band*8 + b, 32 blocks
  const float* fb = bands + (size_t)blk * 262144;  // [4096][64]
  __shared__ float fbs[64][64];
  int t = threadIdx.x;
  int c2 = t & 63;
  int a  = t >> 6;        // 0..3 (wave id)
  float acc[16];
  #pragma unroll
  for (int q = 0; q < 16; ++q) acc[q] = 0.f;
  #pragma unroll 1
  for (int chunk = 0; chunk < 64; ++chunk) {
    #pragma unroll
    for (int i = 0; i < 16; ++i) {
      int e = t + i * 256;
      fbs[e >> 6][e & 63] = fb[(size_t)chunk * 4096 + e];
    }
    __syncthreads();
    #pragma unroll 1
    for (int rr = 0; rr < 64; ++rr) {
      float v2 = fbs[rr][c2];
      const float4* row4 = (const float4*)&fbs[rr][a * 16];
      #pragma unroll
      for (int q4 = 0; q4 < 4; ++q4) {
        float4 va = row4[q4];
        acc[q4 * 4 + 0] += va.x * v2;
        acc[q4 * 4 + 1] += va.y * v2;
        acc[q4 * 4 + 2] += va.z * v2;
        acc[q4 * 4 + 3] += va.w * v2;
      }
    }
    __syncthreads();
  }
  #pragma unroll
  for (int q = 0; q < 16; ++q)
    G[(size_t)blk * 4096 + (a * 16 + q) * 64 + c2] = acc[q];
}

// ---------------- K4: att = softmax(Wq^T G Wk / 8); M = Wv @ att ----------------
__global__ __launch_bounds__(256) void k_att(const float* __restrict__ G,
                                             const float* __restrict__ Wq,
                                             const float* __restrict__ Wk,
                                             const float* __restrict__ Wv,
                                             float* __restrict__ Mout) {
  int blk = blockIdx.x;        // band*8 + b
  int band = blk >> 3;
  __shared__ float Gs[64][68];
  __shared__ float As[64][68];
  __shared__ float Bs[64][68];
  int t = threadIdx.x;
  #pragma unroll
  for (int p = 0; p < 16; ++p) {
    int e = t + p * 256;
    Gs[e >> 6][e & 63] = G[(size_t)blk * 4096 + e];
    As[e >> 6][e & 63] = Wk[(size_t)band * 4096 + e];
  }
  __syncthreads();
  int r  = t >> 2;
  int d0 = (t & 3) << 4;
  float acc[16];
  // T1 = G @ Wk
  #pragma unroll
  for (int q = 0; q < 16; ++q) acc[q] = 0.f;
  #pragma unroll 1
  for (int e = 0; e < 64; ++e) {
    float gv = Gs[r][e];
    const float4* wr = (const float4*)&As[e][d0];
    #pragma unroll
    for (int q4 = 0; q4 < 4; ++q4) {
      float4 wv = wr[q4];
      acc[q4*4+0] += gv * wv.x; acc[q4*4+1] += gv * wv.y;
      acc[q4*4+2] += gv * wv.z; acc[q4*4+3] += gv * wv.w;
    }
  }
  __syncthreads();   // all reads of As(Wk)/Gs done
  #pragma unroll
  for (int q = 0; q < 16; ++q) Bs[r][d0 + q] = acc[q];
  #pragma unroll
  for (int p = 0; p < 16; ++p) {
    int e = t + p * 256;
    As[e >> 6][e & 63] = Wq[(size_t)band * 4096 + e];
  }
  __syncthreads();
  // att = Wq^T T1 / 8
  #pragma unroll
  for (int q = 0; q < 16; ++q) acc[q] = 0.f;
  #pragma unroll 1
  for (int e = 0; e < 64; ++e) {
    float qv = As[e][r];
    const float4* tr = (const float4*)&Bs[e][d0];
    #pragma unroll
    for (int q4 = 0; q4 < 4; ++q4) {
      float4 tv = tr[q4];
      acc[q4*4+0] += qv * tv.x; acc[q4*4+1] += qv * tv.y;
      acc[q4*4+2] += qv * tv.z; acc[q4*4+3] += qv * tv.w;
    }
  }
  #pragma unroll
  for (int q = 0; q < 16; ++q) acc[q] *= 0.125f;
  // softmax over row r (4 lanes per row)
  float mx = acc[0];
  #pragma unroll
  for (int q = 1; q < 16; ++q) mx = fmaxf(mx, acc[q]);
  mx = fmaxf(mx, __shfl_xor(mx, 1));
  mx = fmaxf(mx, __shfl_xor(mx, 2));
  float s = 0.f;
  #pragma unroll
  for (int q = 0; q < 16; ++q) { acc[q] = expf(acc[q] - mx); s += acc[q]; }
  s += __shfl_xor(s, 1);
  s += __shfl_xor(s, 2);
  float inv = 1.f / s;
  #pragma unroll
  for (int q = 0; q < 16; ++q) acc[q] *= inv;
  __syncthreads();   // all reads of As(Wq)/Bs done
  #pragma unroll
  for (int q = 0; q < 16; ++q) Gs[r][d0 + q] = acc[q];  // Gs := att
  #pragma unroll
  for (int p = 0; p < 16; ++p) {
    int e = t + p * 256;
    As[e >> 6][e & 63] = Wv[e];
  }
  __syncthreads();
  // M = Wv @ att
  #pragma unroll
  for (int q = 0; q < 16; ++q) acc[q] = 0.f;
  #pragma unroll 1
  for (int e = 0; e < 64; ++e) {
    float wv = As[r][e];
    const float4* ar = (const float4*)&Gs[e][d0];
    #pragma unroll
    for (int q4 = 0; q4 < 4; ++q4) {
      float4 av = ar[q4];
      acc[q4*4+0] += wv * av.x; acc[q4*4+1] += wv * av.y;
      acc[q4*4+2] += wv * av.z; acc[q4*4+3] += wv * av.w;
    }
  }
  #pragma unroll
  for (int q = 0; q < 16; ++q)
    Mout[(size_t)blk * 4096 + r * 64 + d0 + q] = acc[q];
}

// ---------------- K5: fused W-axis IDWT + channel mix -> lo, hi ----------------
__global__ __launch_bounds__(512) void k_wmerge(const float* __restrict__ mp,
                                                const float* __restrict__ M,
                                                float* __restrict__ lo,
                                                float* __restrict__ hi) {
  int b = blockIdx.x >> 7;
  int h = blockIdx.x & 127;
  __shared__ float mps[128][65];
  __shared__ float Ms[4][64][64];
  int t = threadIdx.x;
  // stage mp row [128][64]
  const float* mrow = mp + (size_t)(b * 128 + h) * (WP * NC);
  #pragma unroll
  for (int i = 0; i < 16; ++i) {
    int e = t + i * 512;
    mps[e >> 6][e & 63] = mrow[e];
  }
  // stage M0..M3 for batch b
  #pragma unroll
  for (int i = 0; i < 32; ++i) {
    int e = t + i * 512;           // 0..16383
    int mat = e >> 12;
    Ms[mat][(e >> 6) & 63][e & 63] = M[((size_t)(mat * 8 + b) << 12) + (e & 4095)];
  }
  __syncthreads();
  int half = t >> 8;       // 0 -> lo, 1 -> hi
  int n    = t & 255;
  int par  = n & 1;
  int mj[4]; float cl[4], cg[4];
  #pragma unroll
  for (int j = 0; j < 4; ++j) {
    mj[j] = ((n >> 1) - j) & 127;
    cl[j] = c_h[par + 2 * j];
    cg[j] = c_g[par + 2 * j];
  }
  const int ma = half * 2, mb = half * 2 + 1;
  float acc[64];
  #pragma unroll
  for (int q = 0; q < 64; ++q) acc[q] = 0.f;
  #pragma unroll 1
  for (int a_ = 0; a_ < 64; ++a_) {
    float v0 = mps[mj[0]][a_], v1 = mps[mj[1]][a_];
    float v2 = mps[mj[2]][a_], v3 = mps[mj[3]][a_];
    float u0 = cl[0]*v0 + cl[1]*v1 + cl[2]*v2 + cl[3]*v3;
    float u1 = cg[0]*v0 + cg[1]*v1 + cg[2]*v2 + cg[3]*v3;
    const float4* r0 = (const float4*)Ms[ma][a_];
    const float4* r1 = (const float4*)Ms[mb][a_];
    #pragma unroll
    for (int q = 0; q < 16; ++q) {
      float4 w0 = r0[q], w1 = r1[q];
      acc[4*q+0] += u0*w0.x + u1*w1.x;
      acc[4*q+1] += u0*w0.y + u1*w1.y;
      acc[4*q+2] += u0*w0.z + u1*w1.z;
      acc[4*q+3] += u0*w0.w + u1*w1.w;
    }
  }
  float* dst = (half ? hi : lo) + ((size_t)(b * 128 + h) * 256 + n) * NC;
  #pragma unroll
  for (int q = 0; q < 16; ++q)
    ((float4*)dst)[q] = make_float4(acc[4*q+0], acc[4*q+1], acc[4*q+2], acc[4*q+3]);
}

// ---------------- K6: depthwise conv + H-axis IDWT -> x (= path_a+path_b) ----------------
// XCD-chunked: b = blk&7 so XCD k owns batch k (halo rows stay in its L2).
// Thread = 4-channel group x 8 cols; all traffic is 16B dwordx4.
__global__ __launch_bounds__(512) void k_convmerge(const float* __restrict__ img,
                                                   const float* __restrict__ ker,
                                                   const float* __restrict__ lo,
                                                   const float* __restrict__ hi,
                                                   float* __restrict__ x) {
  int blk = blockIdx.x;          // 1024
  int b = blk & 7;
  int r = blk >> 3;              // output rows 2r, 2r+1
  __shared__ float ks[49][64];
  int t = threadIdx.x;
  #pragma unroll
  for (int i = 0; i < 7; ++i) {
    int e = t + i * 512;
    if (e < 3136) ks[e >> 6][e & 63] = ker[e];
  }
  __syncthreads();
  int cg = t & 15;               // channel group: c0 = cg*4
  int c0 = cg << 2;
  int wg = t >> 4;               // 0..31, cols w0..w0+7
  int w0 = wg << 3;
  #pragma unroll 1
  for (int nn = 0; nn < 2; ++nn) {
    int n = 2 * r + nn;
    f32x4 acc[8];
    #pragma unroll
    for (int q = 0; q < 8; ++q) acc[q] = (f32x4){0.f, 0.f, 0.f, 0.f};
    // depthwise conv, SAME zero padding
    #pragma unroll 1
    for (int dy = 0; dy < 7; ++dy) {
      int row = n - 3 + dy;
      if (row < 0 || row >= NH) continue;
      const float* ibase = img + ((size_t)(b * NH + row) * NW) * NC + c0;
      f32x4 win[14];
      #pragma unroll
      for (int i2 = 0; i2 < 14; ++i2) {
        int col = w0 - 3 + i2;
        win[i2] = (col >= 0 && col < NW) ? *(const f32x4*)(ibase + (size_t)col * NC)
                                         : (f32x4){0.f, 0.f, 0.f, 0.f};
      }
      #pragma unroll
      for (int dx = 0; dx < 7; ++dx) {
        f32x4 kv = *(const f32x4*)&ks[dy * 7 + dx][c0];
        #pragma unroll
        for (int ww = 0; ww < 8; ++ww) acc[ww] += kv * win[ww + dx];
      }
    }
    // H-merge: rows (r-j)&127 of lo/hi
    int par = n & 1;
    #pragma unroll
    for (int j = 0; j < 4; ++j) {
      int mrow = (r - j) & 127;
      float clv = c_h[par + 2 * j];
      float cgv = c_g[par + 2 * j];
      const float* lb = lo + ((size_t)(b * 128 + mrow) * 256 + w0) * NC + c0;
      const float* hb = hi + ((size_t)(b * 128 + mrow) * 256 + w0) * NC + c0;
      #pragma unroll
      for (int ww = 0; ww < 8; ++ww) {
        f32x4 lv = *(const f32x4*)(lb + (size_t)ww * NC);
        f32x4 hv = *(const f32x4*)(hb + (size_t)ww * NC);
        acc[ww] += clv * lv + cgv * hv;
      }
    }
    float* xb = x + ((size_t)(b * NH + n) * NW + w0) * NC + c0;
    #pragma unroll
    for (int ww = 0; ww < 8; ++ww) *(f32x4*)(xb + (size_t)ww * NC) = acc[ww];
  }
}

// ---------------- K7: LayerNorm + MLP via bf16 MFMA ----------------
// 512 thr / 128 pixels per block; hidden in 4 quarters of 64.
// LDS: x[128][72] + h[128][72] + W1q[64][72] + W2q[64][72] bf16 = 55296 B.
__global__ __launch_bounds__(512, 1) void k_mlp(const float* __restrict__ xin,
                                                const float* __restrict__ gamma,
                                                const float* __restrict__ beta,
                                                const unsigned short* __restrict__ w1t,
                                                const float* __restrict__ b1,
                                                const unsigned short* __restrict__ w2t,
                                                const float* __restrict__ b2,
                                                float* __restrict__ out) {
  __shared__ unsigned short x_s[128 * 72];
  __shared__ unsigned short h_s[128 * 72];
  __shared__ unsigned short w1_s[64 * 72];
  __shared__ unsigned short w2_s[64 * 72];
  int t = threadIdx.x;
  size_t pix0 = (size_t)blockIdx.x * 128;

  // ---- LN: 4 threads per pixel, 16 channels each ----
  {
    int pj = t >> 2, ch0 = (t & 3) * 16;
    const float* xp = xin + (pix0 + pj) * 64 + ch0;
    float xv[16];
    #pragma unroll
    for (int q = 0; q < 4; ++q) {
      float4 v = ((const float4*)xp)[q];
      xv[4*q+0] = v.x; xv[4*q+1] = v.y; xv[4*q+2] = v.z; xv[4*q+3] = v.w;
    }
    float sp = 0.f;
    #pragma unroll
    for (int i = 0; i < 16; ++i) sp += xv[i];
    sp += __shfl_xor(sp, 1);
    sp += __shfl_xor(sp, 2);
    float mu = sp * 0.015625f;
    float vp = 0.f;
    #pragma unroll
    for (int i = 0; i < 16; ++i) { float d = xv[i] - mu; vp += d * d; }
    vp += __shfl_xor(vp, 1);
    vp += __shfl_xor(vp, 2);
    float rs = rsqrtf(vp * 0.015625f + 1e-3f);
    const float4* gp = (const float4*)(gamma + ch0);
    const float4* bp = (const float4*)(beta + ch0);
    bf16x8 o0, o1;
    #pragma unroll
    for (int q = 0; q < 4; ++q) {
      float4 g = gp[q], bb = bp[q];
      unsigned short e0 = f2b((xv[4*q+0] - mu) * rs * g.x + bb.x);
      unsigned short e1 = f2b((xv[4*q+1] - mu) * rs * g.y + bb.y);
      unsigned short e2 = f2b((xv[4*q+2] - mu) * rs * g.z + bb.z);
      unsigned short e3 = f2b((xv[4*q+3] - mu) * rs * g.w + bb.w);
      if (q < 2) { o0[4*q+0]=(short)e0; o0[4*q+1]=(short)e1; o0[4*q+2]=(short)e2; o0[4*q+3]=(short)e3; }
      else { o1[4*(q-2)+0]=(short)e0; o1[4*(q-2)+1]=(short)e1; o1[4*(q-2)+2]=(short)e2; o1[4*(q-2)+3]=(short)e3; }
    }
    *(bf16x8*)&x_s[pj * 72 + ch0] = o0;
    *(bf16x8*)&x_s[pj * 72 + ch0 + 8] = o1;
  }

  const int w  = t >> 6;        // wave 0..7 -> pixels 16w..16w+15
  const int l  = t & 63;
  const int ar = l & 15;
  const int ko = (l >> 4) * 8;
  const int sn = t >> 3;        // staging: row 0..63
  const int sk = (t & 7) * 8;   // staging: col 0..56

  f32x4 acc2[4];
  #pragma unroll
  for (int nt = 0; nt < 4; ++nt) acc2[nt] = (f32x4){0.f, 0.f, 0.f, 0.f};

  #pragma unroll 1
  for (int q = 0; q < 4; ++q) {
    __syncthreads();   // protect w1_s/w2_s/h_s overwrite vs previous reads (and x_s writes at q=0)
    *(bf16x8*)&w1_s[sn * 72 + sk] = *(const bf16x8*)&w1t[(q * 64 + sn) * 64 + sk];
    *(bf16x8*)&w2_s[sn * 72 + sk] = *(const bf16x8*)&w2t[sn * 256 + q * 64 + sk];
    __syncthreads();
    // ---- GEMM1 quarter: h[128][64] = x[128][64] @ W1q[64][64], +b1, GELU ----
    const unsigned short* abase = &x_s[(w * 16 + ar) * 72];
    #pragma unroll
    for (int nt = 0; nt < 4; ++nt) {
      f32x4 acc = (f32x4){0.f, 0.f, 0.f, 0.f};
      const unsigned short* bbase = &w1_s[(nt * 16 + ar) * 72];
      acc = __builtin_amdgcn_mfma_f32_16x16x32_bf16(*(const bf16x8*)(abase + ko),
                                                    *(const bf16x8*)(bbase + ko), acc, 0, 0, 0);
      acc = __builtin_amdgcn_mfma_f32_16x16x32_bf16(*(const bf16x8*)(abase + 32 + ko),
                                                    *(const bf16x8*)(bbase + 32 + ko), acc, 0, 0, 0);
      int col = nt * 16 + ar;
      float bv = b1[q * 64 + col];
      #pragma unroll
      for (int r = 0; r < 4; ++r) {
        int pr = w * 16 + (l >> 4) * 4 + r;
        float hv = acc[r] + bv;
        float gl = 0.5f * hv * (1.f + erff(hv * 0.70710678118654752f));
        h_s[pr * 72 + col] = f2b(gl);
      }
    }
    __syncthreads();
    // ---- GEMM2 partial: out[128][64] += h[128][64] @ W2q[64][64] ----
    const unsigned short* a2base = &h_s[(w * 16 + ar) * 72];
    #pragma unroll
    for (int nt = 0; nt < 4; ++nt) {
      const unsigned short* b2base = &w2_s[(nt * 16 + ar) * 72];
      acc2[nt] = __builtin_amdgcn_mfma_f32_16x16x32_bf16(*(const bf16x8*)(a2base + ko),
                                                         *(const bf16x8*)(b2base + ko), acc2[nt], 0, 0, 0);
      acc2[nt] = __builtin_amdgcn_mfma_f32_16x16x32_bf16(*(const bf16x8*)(a2base + 32 + ko),
                                                         *(const bf16x8*)(b2base + 32 + ko), acc2[nt], 0, 0, 0);
    }
  }

  // ---- epilogue: +b2, store ----
  #pragma unroll
  for (int nt = 0; nt < 4; ++nt) {
    int col = nt * 16 + ar;
    float bb = b2[col];
    #pragma unroll
    for (int r = 0; r < 4; ++r) {
      int pr = w * 16 + (l >> 4) * 4 + r;
      out[(pix0 + pr) * 64 + col] = acc2[nt][r] + bb;
    }
  }
}

extern "C" void kernel_launch(void* const* d_in, const int* in_sizes, int n_in,
                              void* d_out, int out_size, void* d_ws, size_t ws_size,
                              hipStream_t stream) {
  const float* images = (const float*)d_in[0];
  const float* dwk    = (const float*)d_in[1];
  const float* Wv     = (const float*)d_in[2];
  const float* Wq     = (const float*)d_in[3];
  const float* Wk     = (const float*)d_in[4];
  const float* gamma  = (const float*)d_in[5];
  const float* beta   = (const float*)d_in[6];
  const float* W1     = (const float*)d_in[7];
  const float* b1     = (const float*)d_in[8];
  const float* W2     = (const float*)d_in[9];
  const float* b2     = (const float*)d_in[10];
  float* out = (float*)d_out;
  float* ws  = (float*)d_ws;

  float* mp    = ws;                  // 8,388,608
  float* bands = ws + 8388608;        // 8,388,608 (4 bands)
  float* G     = ws + 16777216;       // 131,072
  float* Mm    = ws + 16908288;       // 131,072
  float* lo    = ws + 17039360;       // 16,777,216
  float* hi    = ws + 33816576;       // 16,777,216
  float* tLo   = lo;                  // DWT temps alias lo/hi (dead before overwrite)
  float* tHi   = hi;
  unsigned short* w1t = (unsigned short*)(ws + 50593792);  // 16384 bf16
  unsigned short* w2t = w1t + 16384;                       // 16384 bf16

  k_prep<<<1, 256, 0, stream>>>(W1, W2, w1t, w2t);
  k_maxpool<<<32768, 256, 0, stream>>>(images, mp);
  k_dwt_h<<<16384, 256, 0, stream>>>(mp, tLo, tHi);
  k_dwt_w<<<8192, 256, 0, stream>>>(tLo, tHi, bands);
  k_gram<<<32, 256, 0, stream>>>(bands, G);
  k_att<<<32, 256, 0, stream>>>(G, Wq, Wk, Wv, Mm);
  k_wmerge<<<1024, 512, 0, stream>>>(mp, Mm, lo, hi);
  k_convmerge<<<1024, 512, 0, stream>>>(images, dwk, lo, hi, out);
  k_mlp<<<4096, 512, 0, stream>>>(out, gamma, beta, w1t, b1, w2t, b2, out);
}

// Round 10
// 936.887 us; speedup vs baseline: 37.0058x; 1.2780x over previous
//
#include <hip/hip_runtime.h>
#include <math.h>

#define NB 8
#define NH 256
#define NW 256
#define NC 64
#define HP 128
#define WP 128

typedef short bf16x8 __attribute__((ext_vector_type(8)));
typedef float f32x4 __attribute__((ext_vector_type(4)));

__device__ inline unsigned short f2b(float f) {
  unsigned u = __float_as_uint(f);
  u += 0x7fffu + ((u >> 16) & 1u);
  return (unsigned short)(u >> 16);
}

// db4 analysis filters (lo = c_h, hi = c_g with g[k] = (-1)^k h[7-k])
__constant__ float c_h[8] = {
  -0.010597401784997278f, 0.032883011666982945f, 0.030841381835986965f,
  -0.18703481171888114f, -0.02798376941698385f, 0.6308807679295904f,
   0.7148465705525415f,   0.23037781330885523f};
__constant__ float c_g[8] = {
   0.23037781330885523f, -0.7148465705525415f,  0.6308807679295904f,
   0.02798376941698385f, -0.18703481171888114f, -0.030841381835986965f,
   0.032883011666982945f, 0.010597401784997278f};

// ---------------- K0: transpose + bf16-cast MLP weights ----------------
__global__ __launch_bounds__(256) void k_prep(const float* __restrict__ W1,
                                              const float* __restrict__ W2,
                                              unsigned short* __restrict__ w1t,
                                              unsigned short* __restrict__ w2t) {
  int t = threadIdx.x;
  for (int e = t; e < 16384; e += 256) {      // W1[k][n], k<64, n<256 -> w1t[n][k]
    w1t[(e & 255) * 64 + (e >> 8)] = f2b(W1[e]);
  }
  for (int e = t; e < 16384; e += 256) {      // W2[k][n], k<256, n<64 -> w2t[n][k]
    w2t[(e & 63) * 256 + (e >> 6)] = f2b(W2[e]);
  }
}

// ---------------- K1: 2x2 maxpool ----------------
__global__ __launch_bounds__(256) void k_maxpool(const float* __restrict__ img,
                                                 float* __restrict__ mp) {
  int idx = blockIdx.x * 256 + threadIdx.x;   // 8*128*128*64 = 8388608
  int c  = idx & 63;
  int wp = (idx >> 6) & 127;
  int hp = (idx >> 13) & 127;
  int b  = idx >> 20;
  const float* p = img + (((size_t)b * NH + 2 * hp) * NW + 2 * wp) * NC + c;
  float v0 = p[0], v1 = p[NC], v2 = p[(size_t)NW * NC], v3 = p[(size_t)NW * NC + NC];
  mp[idx] = fmaxf(fmaxf(v0, v1), fmaxf(v2, v3));
}

// ---------------- K2a: DWT along H (XCD-chunked swizzle: batch k -> XCD k) ----------------
__global__ __launch_bounds__(256) void k_dwt_h(const float* __restrict__ mp,
                                               float* __restrict__ tLo,
                                               float* __restrict__ tHi) {
  int blk = blockIdx.x;                       // 16384 blocks
  int sw  = (blk & 7) * 2048 + (blk >> 3);    // bijective: 16384 % 8 == 0
  int idx = sw * 256 + threadIdx.x;           // 8*64*128*64 = 4194304
  int c = idx & 63;
  int w = (idx >> 6) & 127;
  int m = (idx >> 13) & 63;
  int b = idx >> 19;
  const float* base = mp + (size_t)b * (HP * WP * NC) + (size_t)w * NC + c;
  float lo = 0.f, hi = 0.f;
  #pragma unroll
  for (int k = 0; k < 8; ++k) {
    int r = (2 * m + k) & 127;
    float v = base[(size_t)r * (WP * NC)];
    lo += c_h[k] * v;
    hi += c_g[k] * v;
  }
  tLo[idx] = lo;   // [b][m][w][c]
  tHi[idx] = hi;
}

// ---------------- K2b: DWT along W -> 4 bands (XCD-chunked swizzle) ----------------
__global__ __launch_bounds__(256) void k_dwt_w(const float* __restrict__ tLo,
                                               const float* __restrict__ tHi,
                                               float* __restrict__ bands) {
  int blk = blockIdx.x;                       // 8192 blocks
  int sw  = (blk & 7) * 1024 + (blk >> 3);
  int idx = sw * 256 + threadIdx.x;           // 8*64*64*64 = 2097152
  int c = idx & 63;
  int u = (idx >> 6) & 63;
  int m = (idx >> 12) & 63;
  int b = idx >> 18;
  size_t rowbase = ((size_t)(b * 64 + m) * 128) * NC + c;
  float ll = 0.f, lh = 0.f, hl = 0.f, hh = 0.f;
  #pragma unroll
  for (int k = 0; k < 8; ++k) {
    int w = (2 * u + k) & 127;
    float a = tLo[rowbase + (size_t)w * NC];
    float d = tHi[rowbase + (size_t)w * NC];
    ll += c_h[k] * a;  lh += c_g[k] * a;
    hl += c_h[k] * d;  hh += c_g[k] * d;
  }
  const size_t bs = 2097152;  // 8*64*64*64
  bands[0 * bs + idx] = ll;
  bands[1 * bs + idx] = lh;
  bands[2 * bs + idx] = hl;
  bands[3 * bs + idx] = hh;
}

// ---------------- K3a: split-K partial Gram: 1024 blocks = (band*8+b)*32 + chunk ----------------
__global__ __launch_bounds__(256) void k_gram(const float* __restrict__ bands,
                                              float* __restrict__ partial) {
  int blk = blockIdx.x;                        // 1024
  int bb = blk >> 5;                           // band*8 + b
  int ch = blk & 31;                           // row chunk (128 rows)
  const float* fb = bands + (size_t)bb * 262144 + (size_t)ch * 8192;  // [128][64]
  __shared__ float fbs[64][64];
  int t = threadIdx.x;
  int c2 = t & 63;
  int a  = t >> 6;        // 0..3 (wave id)
  float acc[16];
  #pragma unroll
  for (int q = 0; q < 16; ++q) acc[q] = 0.f;
  #pragma unroll 1
  for (int sub = 0; sub < 2; ++sub) {
    #pragma unroll
    for (int i = 0; i < 16; ++i) {
      int e = t + i * 256;
      fbs[e >> 6][e & 63] = fb[(size_t)sub * 4096 + e];
    }
    __syncthreads();
    #pragma unroll 1
    for (int rr = 0; rr < 64; ++rr) {
      float v2 = fbs[rr][c2];
      const float4* row4 = (const float4*)&fbs[rr][a * 16];
      #pragma unroll
      for (int q4 = 0; q4 < 4; ++q4) {
        float4 va = row4[q4];
        acc[q4 * 4 + 0] += va.x * v2;
        acc[q4 * 4 + 1] += va.y * v2;
        acc[q4 * 4 + 2] += va.z * v2;
        acc[q4 * 4 + 3] += va.w * v2;
      }
    }
    __syncthreads();
  }
  #pragma unroll
  for (int q = 0; q < 16; ++q)
    partial[(size_t)blk * 4096 + (a * 16 + q) * 64 + c2] = acc[q];
}

// ---------------- K3b: reduce 32 partials -> G ----------------
__global__ __launch_bounds__(256) void k_gram_red(const float* __restrict__ partial,
                                                  float* __restrict__ G) {
  int idx = blockIdx.x * 256 + threadIdx.x;    // 131072 = 32 * 4096
  int bb = idx >> 12;
  int e  = idx & 4095;
  const float* p = partial + (size_t)bb * 131072 + e;
  float s = 0.f;
  #pragma unroll
  for (int ch = 0; ch < 32; ++ch) s += p[(size_t)ch * 4096];
  G[idx] = s;
}

// ---------------- K4: att = softmax(Wq^T G Wk / 8); M = Wv @ att ----------------
__global__ __launch_bounds__(256) void k_att(const float* __restrict__ G,
                                             const float* __restrict__ Wq,
                                             const float* __restrict__ Wk,
                                             const float* __restrict__ Wv,
                                             float* __restrict__ Mout) {
  int blk = blockIdx.x;        // band*8 + b
  int band = blk >> 3;
  __shared__ float Gs[64][68];
  __shared__ float As[64][68];
  __shared__ float Bs[64][68];
  int t = threadIdx.x;
  #pragma unroll
  for (int p = 0; p < 16; ++p) {
    int e = t + p * 256;
    Gs[e >> 6][e & 63] = G[(size_t)blk * 4096 + e];
    As[e >> 6][e & 63] = Wk[(size_t)band * 4096 + e];
  }
  __syncthreads();
  int r  = t >> 2;
  int d0 = (t & 3) << 4;
  float acc[16];
  // T1 = G @ Wk
  #pragma unroll
  for (int q = 0; q < 16; ++q) acc[q] = 0.f;
  #pragma unroll 1
  for (int e = 0; e < 64; ++e) {
    float gv = Gs[r][e];
    const float4* wr = (const float4*)&As[e][d0];
    #pragma unroll
    for (int q4 = 0; q4 < 4; ++q4) {
      float4 wv = wr[q4];
      acc[q4*4+0] += gv * wv.x; acc[q4*4+1] += gv * wv.y;
      acc[q4*4+2] += gv * wv.z; acc[q4*4+3] += gv * wv.w;
    }
  }
  __syncthreads();   // all reads of As(Wk)/Gs done
  #pragma unroll
  for (int q = 0; q < 16; ++q) Bs[r][d0 + q] = acc[q];
  #pragma unroll
  for (int p = 0; p < 16; ++p) {
    int e = t + p * 256;
    As[e >> 6][e & 63] = Wq[(size_t)band * 4096 + e];
  }
  __syncthreads();
  // att = Wq^T T1 / 8
  #pragma unroll
  for (int q = 0; q < 16; ++q) acc[q] = 0.f;
  #pragma unroll 1
  for (int e = 0; e < 64; ++e) {
    float qv = As[e][r];
    const float4* tr = (const float4*)&Bs[e][d0];
    #pragma unroll
    for (int q4 = 0; q4 < 4; ++q4) {
      float4 tv = tr[q4];
      acc[q4*4+0] += qv * tv.x; acc[q4*4+1] += qv * tv.y;
      acc[q4*4+2] += qv * tv.z; acc[q4*4+3] += qv * tv.w;
    }
  }
  #pragma unroll
  for (int q = 0; q < 16; ++q) acc[q] *= 0.125f;
  // softmax over row r (4 lanes per row)
  float mx = acc[0];
  #pragma unroll
  for (int q = 1; q < 16; ++q) mx = fmaxf(mx, acc[q]);
  mx = fmaxf(mx, __shfl_xor(mx, 1));
  mx = fmaxf(mx, __shfl_xor(mx, 2));
  float s = 0.f;
  #pragma unroll
  for (int q = 0; q < 16; ++q) { acc[q] = expf(acc[q] - mx); s += acc[q]; }
  s += __shfl_xor(s, 1);
  s += __shfl_xor(s, 2);
  float inv = 1.f / s;
  #pragma unroll
  for (int q = 0; q < 16; ++q) acc[q] *= inv;
  __syncthreads();   // all reads of As(Wq)/Bs done
  #pragma unroll
  for (int q = 0; q < 16; ++q) Gs[r][d0 + q] = acc[q];  // Gs := att
  #pragma unroll
  for (int p = 0; p < 16; ++p) {
    int e = t + p * 256;
    As[e >> 6][e & 63] = Wv[e];
  }
  __syncthreads();
  // M = Wv @ att
  #pragma unroll
  for (int q = 0; q < 16; ++q) acc[q] = 0.f;
  #pragma unroll 1
  for (int e = 0; e < 64; ++e) {
    float wv = As[r][e];
    const float4* ar = (const float4*)&Gs[e][d0];
    #pragma unroll
    for (int q4 = 0; q4 < 4; ++q4) {
      float4 av = ar[q4];
      acc[q4*4+0] += wv * av.x; acc[q4*4+1] += wv * av.y;
      acc[q4*4+2] += wv * av.z; acc[q4*4+3] += wv * av.w;
    }
  }
  #pragma unroll
  for (int q = 0; q < 16; ++q)
    Mout[(size_t)blk * 4096 + r * 64 + d0 + q] = acc[q];
}

// ---------------- K5: fused W-axis IDWT + channel mix -> lo, hi ----------------
__global__ __launch_bounds__(512) void k_wmerge(const float* __restrict__ mp,
                                                const float* __restrict__ M,
                                                float* __restrict__ lo,
                                                float* __restrict__ hi) {
  int b = blockIdx.x >> 7;
  int h = blockIdx.x & 127;
  __shared__ float mps[128][65];
  __shared__ float Ms[4][64][64];
  int t = threadIdx.x;
  // stage mp row [128][64]
  const float* mrow = mp + (size_t)(b * 128 + h) * (WP * NC);
  #pragma unroll
  for (int i = 0; i < 16; ++i) {
    int e = t + i * 512;
    mps[e >> 6][e & 63] = mrow[e];
  }
  // stage M0..M3 for batch b
  #pragma unroll
  for (int i = 0; i < 32; ++i) {
    int e = t + i * 512;           // 0..16383
    int mat = e >> 12;
    Ms[mat][(e >> 6) & 63][e & 63] = M[((size_t)(mat * 8 + b) << 12) + (e & 4095)];
  }
  __syncthreads();
  int half = t >> 8;       // 0 -> lo, 1 -> hi
  int n    = t & 255;
  int par  = n & 1;
  int mj[4]; float cl[4], cg[4];
  #pragma unroll
  for (int j = 0; j < 4; ++j) {
    mj[j] = ((n >> 1) - j) & 127;
    cl[j] = c_h[par + 2 * j];
    cg[j] = c_g[par + 2 * j];
  }
  const int ma = half * 2, mb = half * 2 + 1;
  float acc[64];
  #pragma unroll
  for (int q = 0; q < 64; ++q) acc[q] = 0.f;
  #pragma unroll 1
  for (int a_ = 0; a_ < 64; ++a_) {
    float v0 = mps[mj[0]][a_], v1 = mps[mj[1]][a_];
    float v2 = mps[mj[2]][a_], v3 = mps[mj[3]][a_];
    float u0 = cl[0]*v0 + cl[1]*v1 + cl[2]*v2 + cl[3]*v3;
    float u1 = cg[0]*v0 + cg[1]*v1 + cg[2]*v2 + cg[3]*v3;
    const float4* r0 = (const float4*)Ms[ma][a_];
    const float4* r1 = (const float4*)Ms[mb][a_];
    #pragma unroll
    for (int q = 0; q < 16; ++q) {
      float4 w0 = r0[q], w1 = r1[q];
      acc[4*q+0] += u0*w0.x + u1*w1.x;
      acc[4*q+1] += u0*w0.y + u1*w1.y;
      acc[4*q+2] += u0*w0.z + u1*w1.z;
      acc[4*q+3] += u0*w0.w + u1*w1.w;
    }
  }
  float* dst = (half ? hi : lo) + ((size_t)(b * 128 + h) * 256 + n) * NC;
  #pragma unroll
  for (int q = 0; q < 16; ++q)
    ((float4*)dst)[q] = make_float4(acc[4*q+0], acc[4*q+1], acc[4*q+2], acc[4*q+3]);
}

// ---------------- K6: depthwise conv + H-axis IDWT -> x (= path_a+path_b) ----------------
// XCD-chunked: b = blk&7 so XCD k owns batch k (halo rows stay in its L2).
// Thread = 4-channel group x 8 cols; all traffic is 16B dwordx4.
__global__ __launch_bounds__(512) void k_convmerge(const float* __restrict__ img,
                                                   const float* __restrict__ ker,
                                                   const float* __restrict__ lo,
                                                   const float* __restrict__ hi,
                                                   float* __restrict__ x) {
  int blk = blockIdx.x;          // 1024
  int b = blk & 7;
  int r = blk >> 3;              // output rows 2r, 2r+1
  __shared__ float ks[49][64];
  int t = threadIdx.x;
  #pragma unroll
  for (int i = 0; i < 7; ++i) {
    int e = t + i * 512;
    if (e < 3136) ks[e >> 6][e & 63] = ker[e];
  }
  __syncthreads();
  int cg = t & 15;               // channel group: c0 = cg*4
  int c0 = cg << 2;
  int wg = t >> 4;               // 0..31, cols w0..w0+7
  int w0 = wg << 3;
  #pragma unroll 1
  for (int nn = 0; nn < 2; ++nn) {
    int n = 2 * r + nn;
    f32x4 acc[8];
    #pragma unroll
    for (int q = 0; q < 8; ++q) acc[q] = (f32x4){0.f, 0.f, 0.f, 0.f};
    // depthwise conv, SAME zero padding
    #pragma unroll 1
    for (int dy = 0; dy < 7; ++dy) {
      int row = n - 3 + dy;
      if (row < 0 || row >= NH) continue;
      const float* ibase = img + ((size_t)(b * NH + row) * NW) * NC + c0;
      f32x4 win[14];
      #pragma unroll
      for (int i2 = 0; i2 < 14; ++i2) {
        int col = w0 - 3 + i2;
        win[i2] = (col >= 0 && col < NW) ? *(const f32x4*)(ibase + (size_t)col * NC)
                                         : (f32x4){0.f, 0.f, 0.f, 0.f};
      }
      #pragma unroll
      for (int dx = 0; dx < 7; ++dx) {
        f32x4 kv = *(const f32x4*)&ks[dy * 7 + dx][c0];
        #pragma unroll
        for (int ww = 0; ww < 8; ++ww) acc[ww] += kv * win[ww + dx];
      }
    }
    // H-merge: rows (r-j)&127 of lo/hi
    int par = n & 1;
    #pragma unroll
    for (int j = 0; j < 4; ++j) {
      int mrow = (r - j) & 127;
      float clv = c_h[par + 2 * j];
      float cgv = c_g[par + 2 * j];
      const float* lb = lo + ((size_t)(b * 128 + mrow) * 256 + w0) * NC + c0;
      const float* hb = hi + ((size_t)(b * 128 + mrow) * 256 + w0) * NC + c0;
      #pragma unroll
      for (int ww = 0; ww < 8; ++ww) {
        f32x4 lv = *(const f32x4*)(lb + (size_t)ww * NC);
        f32x4 hv = *(const f32x4*)(hb + (size_t)ww * NC);
        acc[ww] += clv * lv + cgv * hv;
      }
    }
    float* xb = x + ((size_t)(b * NH + n) * NW + w0) * NC + c0;
    #pragma unroll
    for (int ww = 0; ww < 8; ++ww) *(f32x4*)(xb + (size_t)ww * NC) = acc[ww];
  }
}

// ---------------- K7: LayerNorm + MLP via bf16 MFMA ----------------
// 512 thr / 128 pixels per block; hidden in 4 quarters of 64.
// LDS: x[128][72] + h[128][72] + W1q[64][72] + W2q[64][72] bf16 = 55296 B.
__global__ __launch_bounds__(512, 1) void k_mlp(const float* __restrict__ xin,
                                                const float* __restrict__ gamma,
                                                const float* __restrict__ beta,
                                                const unsigned short* __restrict__ w1t,
                                                const float* __restrict__ b1,
                                                const unsigned short* __restrict__ w2t,
                                                const float* __restrict__ b2,
                                                float* __restrict__ out) {
  __shared__ unsigned short x_s[128 * 72];
  __shared__ unsigned short h_s[128 * 72];
  __shared__ unsigned short w1_s[64 * 72];
  __shared__ unsigned short w2_s[64 * 72];
  int t = threadIdx.x;
  size_t pix0 = (size_t)blockIdx.x * 128;

  // ---- LN: 4 threads per pixel, 16 channels each ----
  {
    int pj = t >> 2, ch0 = (t & 3) * 16;
    const float* xp = xin + (pix0 + pj) * 64 + ch0;
    float xv[16];
    #pragma unroll
    for (int q = 0; q < 4; ++q) {
      float4 v = ((const float4*)xp)[q];
      xv[4*q+0] = v.x; xv[4*q+1] = v.y; xv[4*q+2] = v.z; xv[4*q+3] = v.w;
    }
    float sp = 0.f;
    #pragma unroll
    for (int i = 0; i < 16; ++i) sp += xv[i];
    sp += __shfl_xor(sp, 1);
    sp += __shfl_xor(sp, 2);
    float mu = sp * 0.015625f;
    float vp = 0.f;
    #pragma unroll
    for (int i = 0; i < 16; ++i) { float d = xv[i] - mu; vp += d * d; }
    vp += __shfl_xor(vp, 1);
    vp += __shfl_xor(vp, 2);
    float rs = rsqrtf(vp * 0.015625f + 1e-3f);
    const float4* gp = (const float4*)(gamma + ch0);
    const float4* bp = (const float4*)(beta + ch0);
    bf16x8 o0, o1;
    #pragma unroll
    for (int q = 0; q < 4; ++q) {
      float4 g = gp[q], bb = bp[q];
      unsigned short e0 = f2b((xv[4*q+0] - mu) * rs * g.x + bb.x);
      unsigned short e1 = f2b((xv[4*q+1] - mu) * rs * g.y + bb.y);
      unsigned short e2 = f2b((xv[4*q+2] - mu) * rs * g.z + bb.z);
      unsigned short e3 = f2b((xv[4*q+3] - mu) * rs * g.w + bb.w);
      if (q < 2) { o0[4*q+0]=(short)e0; o0[4*q+1]=(short)e1; o0[4*q+2]=(short)e2; o0[4*q+3]=(short)e3; }
      else { o1[4*(q-2)+0]=(short)e0; o1[4*(q-2)+1]=(short)e1; o1[4*(q-2)+2]=(short)e2; o1[4*(q-2)+3]=(short)e3; }
    }
    *(bf16x8*)&x_s[pj * 72 + ch0] = o0;
    *(bf16x8*)&x_s[pj * 72 + ch0 + 8] = o1;
  }

  const int w  = t >> 6;        // wave 0..7 -> pixels 16w..16w+15
  const int l  = t & 63;
  const int ar = l & 15;
  const int ko = (l >> 4) * 8;
  const int sn = t >> 3;        // staging: row 0..63
  const int sk = (t & 7) * 8;   // staging: col 0..56

  f32x4 acc2[4];
  #pragma unroll
  for (int nt = 0; nt < 4; ++nt) acc2[nt] = (f32x4){0.f, 0.f, 0.f, 0.f};

  #pragma unroll 1
  for (int q = 0; q < 4; ++q) {
    __syncthreads();   // protect w1_s/w2_s/h_s overwrite vs previous reads (and x_s writes at q=0)
    *(bf16x8*)&w1_s[sn * 72 + sk] = *(const bf16x8*)&w1t[(q * 64 + sn) * 64 + sk];
    *(bf16x8*)&w2_s[sn * 72 + sk] = *(const bf16x8*)&w2t[sn * 256 + q * 64 + sk];
    __syncthreads();
    // ---- GEMM1 quarter: h[128][64] = x[128][64] @ W1q[64][64], +b1, GELU ----
    const unsigned short* abase = &x_s[(w * 16 + ar) * 72];
    #pragma unroll
    for (int nt = 0; nt < 4; ++nt) {
      f32x4 acc = (f32x4){0.f, 0.f, 0.f, 0.f};
      const unsigned short* bbase = &w1_s[(nt * 16 + ar) * 72];
      acc = __builtin_amdgcn_mfma_f32_16x16x32_bf16(*(const bf16x8*)(abase + ko),
                                                    *(const bf16x8*)(bbase + ko), acc, 0, 0, 0);
      acc = __builtin_amdgcn_mfma_f32_16x16x32_bf16(*(const bf16x8*)(abase + 32 + ko),
                                                    *(const bf16x8*)(bbase + 32 + ko), acc, 0, 0, 0);
      int col = nt * 16 + ar;
      float bv = b1[q * 64 + col];
      #pragma unroll
      for (int r = 0; r < 4; ++r) {
        int pr = w * 16 + (l >> 4) * 4 + r;
        float hv = acc[r] + bv;
        float gl = 0.5f * hv * (1.f + erff(hv * 0.70710678118654752f));
        h_s[pr * 72 + col] = f2b(gl);
      }
    }
    __syncthreads();
    // ---- GEMM2 partial: out[128][64] += h[128][64] @ W2q[64][64] ----
    const unsigned short* a2base = &h_s[(w * 16 + ar) * 72];
    #pragma unroll
    for (int nt = 0; nt < 4; ++nt) {
      const unsigned short* b2base = &w2_s[(nt * 16 + ar) * 72];
      acc2[nt] = __builtin_amdgcn_mfma_f32_16x16x32_bf16(*(const bf16x8*)(a2base + ko),
                                                         *(const bf16x8*)(b2base + ko), acc2[nt], 0, 0, 0);
      acc2[nt] = __builtin_amdgcn_mfma_f32_16x16x32_bf16(*(const bf16x8*)(a2base + 32 + ko),
                                                         *(const bf16x8*)(b2base + 32 + ko), acc2[nt], 0, 0, 0);
    }
  }

  // ---- epilogue: +b2, store ----
  #pragma unroll
  for (int nt = 0; nt < 4; ++nt) {
    int col = nt * 16 + ar;
    float bb = b2[col];
    #pragma unroll
    for (int r = 0; r < 4; ++r) {
      int pr = w * 16 + (l >> 4) * 4 + r;
      out[(pix0 + pr) * 64 + col] = acc2[nt][r] + bb;
    }
  }
}

extern "C" void kernel_launch(void* const* d_in, const int* in_sizes, int n_in,
                              void* d_out, int out_size, void* d_ws, size_t ws_size,
                              hipStream_t stream) {
  const float* images = (const float*)d_in[0];
  const float* dwk    = (const float*)d_in[1];
  const float* Wv     = (const float*)d_in[2];
  const float* Wq     = (const float*)d_in[3];
  const float* Wk     = (const float*)d_in[4];
  const float* gamma  = (const float*)d_in[5];
  const float* beta   = (const float*)d_in[6];
  const float* W1     = (const float*)d_in[7];
  const float* b1     = (const float*)d_in[8];
  const float* W2     = (const float*)d_in[9];
  const float* b2     = (const float*)d_in[10];
  float* out = (float*)d_out;
  float* ws  = (float*)d_ws;

  float* mp    = ws;                  // 8,388,608
  float* bands = ws + 8388608;        // 8,388,608 (4 bands)
  float* G     = ws + 16777216;       // 131,072
  float* Mm    = ws + 16908288;       // 131,072
  float* lo    = ws + 17039360;       // 16,777,216
  float* hi    = ws + 33816576;       // 16,777,216
  float* tLo   = lo;                  // DWT temps alias lo/hi (dead before overwrite)
  float* tHi   = hi;
  float* gpart = lo;                  // split-K Gram partials (4,194,304 floats) alias lo:
                                      //   dwt temps dead after k_dwt_w; wmerge overwrites later
  unsigned short* w1t = (unsigned short*)(ws + 50593792);  // 16384 bf16
  unsigned short* w2t = w1t + 16384;                       // 16384 bf16

  k_prep<<<1, 256, 0, stream>>>(W1, W2, w1t, w2t);
  k_maxpool<<<32768, 256, 0, stream>>>(images, mp);
  k_dwt_h<<<16384, 256, 0, stream>>>(mp, tLo, tHi);
  k_dwt_w<<<8192, 256, 0, stream>>>(tLo, tHi, bands);
  k_gram<<<1024, 256, 0, stream>>>(bands, gpart);
  k_gram_red<<<512, 256, 0, stream>>>(gpart, G);
  k_att<<<32, 256, 0, stream>>>(G, Wq, Wk, Wv, Mm);
  k_wmerge<<<1024, 512, 0, stream>>>(mp, Mm, lo, hi);
  k_convmerge<<<1024, 512, 0, stream>>>(images, dwk, lo, hi, out);
  k_mlp<<<4096, 512, 0, stream>>>(out, gamma, beta, w1t, b1, w2t, b2, out);
}